// Round 5
// baseline (165.077 us; speedup 1.0000x reference)
//
#include <hip/hip_runtime.h>
#include <hip/hip_fp16.h>

#define BATCH 8
#define S_LOG 9
#define SBUCKET 512          // nodes per bucket
#define KC 256               // max buckets (N <= 131071)
#define CB 2048              // blocks for count/scatter (chunk ~1568 <= TTILE)
#define TTILE 2048           // edges per sort tile
#define EPT 8                // edges per thread per tile (contiguous)
#define MA 10                // accum sub-blocks per bucket (196*10=1960 ~ 8/CU)

static inline size_t alignup(size_t x) { return (x + 255) & ~(size_t)255; }

__device__ __forceinline__ unsigned bf16hi(unsigned u) {
    // fp32 -> bf16 (rne), returned in LOW 16 bits
    return (u + 0x7FFFu + ((u >> 16) & 1u)) >> 16;
}

__device__ __forceinline__ int aligned_chunk(int E) {
    return (((E + CB - 1) / CB) + 15) & ~15;    // 16-elem aligned => 64B
}

// ---------------- pipeline kernels ----------------

// fused: blocks [0,CB) bucket-count (int4 loads, uint LDS atomics); blocks [CB,...)
// transpose y -> yT[node] = 8 bf16 (uint4)
__global__ __launch_bounds__(256)
void count_transpose_kernel(const int* __restrict__ ei0, unsigned* __restrict__ counts,
                            const float* __restrict__ y, uint4* __restrict__ yT,
                            int E, int N, int Npad) {
    __shared__ unsigned cnt[KC];
    int tid = threadIdx.x;
    if (blockIdx.x >= CB) {
        int n = (blockIdx.x - CB) * 256 + tid;
        if (n < Npad) {
            uint4 o = make_uint4(0u, 0u, 0u, 0u);
            if (n < N) {
                unsigned p[8];
#pragma unroll
                for (int b = 0; b < BATCH; ++b)
                    p[b] = bf16hi(__float_as_uint(y[(size_t)b * N + n]));
                o = make_uint4(p[0] | (p[1] << 16), p[2] | (p[3] << 16),
                               p[4] | (p[5] << 16), p[6] | (p[7] << 16));
            }
            yT[n] = o;
        }
        return;
    }
    cnt[tid] = 0;
    __syncthreads();
    int chunk = aligned_chunk(E);
    int lo = blockIdx.x * chunk;
    int hi = min(lo + chunk, E);
    for (int bi = lo; bi < hi; bi += 1024) {
        int idx = bi + tid * 4;
        if (idx + 4 <= hi) {
            int4 v = *(const int4*)(ei0 + idx);
            atomicAdd(&cnt[(unsigned)v.x >> S_LOG], 1u);
            atomicAdd(&cnt[(unsigned)v.y >> S_LOG], 1u);
            atomicAdd(&cnt[(unsigned)v.z >> S_LOG], 1u);
            atomicAdd(&cnt[(unsigned)v.w >> S_LOG], 1u);
        } else {
#pragma unroll
            for (int j = 0; j < 4; ++j) {
                int i2 = idx + j;
                if (i2 < hi) atomicAdd(&cnt[(unsigned)ei0[i2] >> S_LOG], 1u);
            }
        }
    }
    __syncthreads();
    counts[(size_t)tid * CB + blockIdx.x] = cnt[tid];   // [bucket][block]
}

// scanB1: one block per bucket — local exclusive prefix of counts[k][0..CB) -> base,
// and bucket total -> tot[k]. CB=2048: each thread owns 8 contiguous blocks
// [8*tid, 8*tid+8) via two uint4 loads.
__global__ __launch_bounds__(256)
void scanB1_kernel(const unsigned* __restrict__ counts, unsigned* __restrict__ base,
                   unsigned* __restrict__ tot) {
    __shared__ unsigned ssum[256];
    int k = blockIdx.x, tid = threadIdx.x;
    const uint4* row4 = (const uint4*)(counts + (size_t)k * CB);
    uint4 v0 = row4[2 * tid];
    uint4 v1 = row4[2 * tid + 1];
    unsigned s0 = v0.x + v0.y + v0.z + v0.w;
    unsigned lsum = s0 + v1.x + v1.y + v1.z + v1.w;
    ssum[tid] = lsum;
    __syncthreads();
    for (int off = 1; off < 256; off <<= 1) {
        unsigned u = ssum[tid];
        unsigned a = (tid >= off) ? ssum[tid - off] : 0u;
        __syncthreads();
        ssum[tid] = u + a;
        __syncthreads();
    }
    unsigned ex = ssum[tid] - lsum;
    if (tid == 255) tot[k] = ssum[255];
    uint4 o0, o1;
    o0.x = ex;
    o0.y = ex + v0.x;
    o0.z = o0.y + v0.y;
    o0.w = o0.z + v0.z;
    unsigned s4 = ex + s0;
    o1.x = s4;
    o1.y = s4 + v1.x;
    o1.z = o1.y + v1.y;
    o1.w = o1.z + v1.z;
    uint4* brow = (uint4*)(base + (size_t)k * CB);
    brow[2 * tid]     = o0;
    brow[2 * tid + 1] = o1;
}

// scanC: one block — exclusive scan of bucket totals -> bb[0..KC], bb[KC]=E
__global__ void scanC_kernel(const unsigned* __restrict__ tot,
                             unsigned* __restrict__ bb, int E, int K) {
    __shared__ unsigned sb[KC];
    int t = threadIdx.x;
    unsigned v = (t < K) ? tot[t] : 0u;
    sb[t] = v;
    __syncthreads();
    for (int off = 1; off < KC; off <<= 1) {
        unsigned u = sb[t];
        unsigned a = (t >= off) ? sb[t - off] : 0u;
        __syncthreads();
        sb[t] = u + a;
        __syncthreads();
    }
    bb[t] = sb[t] - v;
    if (t == KC - 1) bb[KC] = (unsigned)E;
}

// scatter: bucket-sort edges into w0coef records (uint LDS atomics — cheap).
// Per-thread CONTIGUOUS EPT elements => int4/float4 vector loads.
// record: .x = s1 | s0l<<17 ; .y = bf16(coef)<<16 | bf16(gea)
__global__ __launch_bounds__(256)
void scatter_kernel(const int* __restrict__ ei0, const int* __restrict__ ei1,
                    const float* __restrict__ dw, const float* __restrict__ gea,
                    const unsigned* __restrict__ base, const unsigned* __restrict__ bb,
                    uint2* __restrict__ w0coef, int E) {
    __shared__ unsigned cursor[KC];
    __shared__ unsigned h[KC];
    __shared__ unsigned tstart[KC];
    __shared__ unsigned wsum[4];
    __shared__ uint2 srec[TTILE];            // 16 KB
    __shared__ unsigned char skey[TTILE];    // 2 KB
    int tid = threadIdx.x;
    cursor[tid] = base[(size_t)tid * CB + blockIdx.x] + bb[tid];
    int chunk = aligned_chunk(E);
    int lo = blockIdx.x * chunk;
    int hi = min(lo + chunk, E);
    __syncthreads();

    for (int tileLo = lo; tileLo < hi; tileLo += TTILE) {
        int tn = min(TTILE, hi - tileLo);
        h[tid] = 0;
        __syncthreads();

        int base_off = tid * EPT;
        unsigned k_r[EPT], w0_r[EPT], pk_r[EPT], rk_r[EPT];
        int s0a[EPT], s1a[EPT];
        float dwa[EPT], gea_a[EPT];
        bool anyv = base_off < tn;
        if (base_off + EPT <= tn) {
            // vector loads (tileLo 16-aligned, base_off multiple of 8)
            const int4* p0 = (const int4*)(ei0 + tileLo + base_off);
            const int4* p1 = (const int4*)(ei1 + tileLo + base_off);
            const float4* pd = (const float4*)(dw + tileLo + base_off);
            const float4* pg = (const float4*)(gea + tileLo + base_off);
            int4 a0 = p0[0], a1 = p0[1];
            int4 b0 = p1[0], b1 = p1[1];
            float4 d0 = pd[0], d1 = pd[1];
            float4 g0 = pg[0], g1 = pg[1];
            s0a[0]=a0.x; s0a[1]=a0.y; s0a[2]=a0.z; s0a[3]=a0.w;
            s0a[4]=a1.x; s0a[5]=a1.y; s0a[6]=a1.z; s0a[7]=a1.w;
            s1a[0]=b0.x; s1a[1]=b0.y; s1a[2]=b0.z; s1a[3]=b0.w;
            s1a[4]=b1.x; s1a[5]=b1.y; s1a[6]=b1.z; s1a[7]=b1.w;
            dwa[0]=d0.x; dwa[1]=d0.y; dwa[2]=d0.z; dwa[3]=d0.w;
            dwa[4]=d1.x; dwa[5]=d1.y; dwa[6]=d1.z; dwa[7]=d1.w;
            gea_a[0]=g0.x; gea_a[1]=g0.y; gea_a[2]=g0.z; gea_a[3]=g0.w;
            gea_a[4]=g1.x; gea_a[5]=g1.y; gea_a[6]=g1.z; gea_a[7]=g1.w;
#pragma unroll
            for (int j = 0; j < EPT; ++j) k_r[j] = 0u;   // mark all valid below
#pragma unroll
            for (int j = 0; j < EPT; ++j) {
                unsigned k = (unsigned)s0a[j] >> S_LOG;
                unsigned s0l = (unsigned)(s0a[j] & (SBUCKET - 1));
                k_r[j] = k;
                w0_r[j] = (unsigned)s1a[j] | (s0l << 17);
                float sig = 1.0f / (1.0f + __expf(-dwa[j]));
                pk_r[j] = (bf16hi(__float_as_uint(sqrtf(sig))) << 16) |
                          bf16hi(__float_as_uint(gea_a[j]));
            }
#pragma unroll
            for (int j = 0; j < EPT; ++j)
                rk_r[j] = atomicAdd(&h[k_r[j]], 1u);
        } else {
#pragma unroll
            for (int j = 0; j < EPT; ++j) {
                int off = base_off + j;
                k_r[j] = 0xFFFFFFFFu;
                if (off < tn) {
                    int i = tileLo + off;
                    int s0v = ei0[i];
                    int s1v = ei1[i];
                    unsigned k = (unsigned)s0v >> S_LOG;
                    unsigned s0l = (unsigned)(s0v & (SBUCKET - 1));
                    k_r[j] = k;
                    w0_r[j] = (unsigned)s1v | (s0l << 17);
                    float sig = 1.0f / (1.0f + __expf(-dw[i]));
                    pk_r[j] = (bf16hi(__float_as_uint(sqrtf(sig))) << 16) |
                              bf16hi(__float_as_uint(gea[i]));
                }
            }
#pragma unroll
            for (int j = 0; j < EPT; ++j)
                if (k_r[j] != 0xFFFFFFFFu) rk_r[j] = atomicAdd(&h[k_r[j]], 1u);
        }
        bool fullv = base_off + EPT <= tn;
        __syncthreads();

        // exclusive scan of h[256] via wave shuffles
        unsigned hv = h[tid];
        unsigned v = hv;
        unsigned lane = tid & 63;
        unsigned wv = tid >> 6;
#pragma unroll
        for (int off = 1; off < 64; off <<= 1) {
            unsigned t = __shfl_up(v, off, 64);
            if (lane >= off) v += t;
        }
        if (lane == 63) wsum[wv] = v;
        __syncthreads();
        unsigned addv = 0;
#pragma unroll
        for (unsigned w = 0; w < 4; ++w)
            if (w < wv) addv += wsum[w];
        tstart[tid] = v + addv - hv;
        __syncthreads();

        if (fullv) {
#pragma unroll
            for (int j = 0; j < EPT; ++j) {
                unsigned slot = tstart[k_r[j]] + rk_r[j];
                srec[slot] = make_uint2(w0_r[j], pk_r[j]);
                skey[slot] = (unsigned char)k_r[j];
            }
        } else if (anyv) {
#pragma unroll
            for (int j = 0; j < EPT; ++j)
                if (k_r[j] != 0xFFFFFFFFu) {
                    unsigned slot = tstart[k_r[j]] + rk_r[j];
                    srec[slot] = make_uint2(w0_r[j], pk_r[j]);
                    skey[slot] = (unsigned char)k_r[j];
                }
        }
        __syncthreads();

        for (int i = tid; i < tn; i += 256) {
            uint2 u = srec[i];
            unsigned k = skey[i];
            unsigned pos = cursor[k] + ((unsigned)i - tstart[k]);
            w0coef[pos] = u;
        }
        __syncthreads();
        cursor[tid] += h[tid];
        __syncthreads();
    }
}

// main accumulation: grid (K, MA), 128 threads (2 waves) — NO LDS f32 atomics
// (measured R1: ds_add_f32 is ~3.7 cy/lane -> 4x slower than this scheme).
// Per-wave private fp16-pair accumulators; duplicates resolved by 9-bit ballot
// grouping + rank-ordered plain RMW rounds. y0 read from yT via L1.
__global__ __launch_bounds__(128)
void accum_kernel(const uint2* __restrict__ w0coef, const unsigned* __restrict__ bb,
                  const uint4* __restrict__ yT,
                  float* __restrict__ pdegp, __half2* __restrict__ pout,
                  int N, int Npad) {
    __shared__ __half2 outw[2][4][SBUCKET];       // 16 KB: [wave][batchpair][node]
    __shared__ float  degw[2][SBUCKET];           // 4 KB:  [wave][node]
    int k = blockIdx.x, m = blockIdx.y, tid = threadIdx.x;
    int n0 = k << S_LOG;
    unsigned lane = tid & 63;
    unsigned wv = tid >> 6;

    for (int i = tid; i < 2 * 4 * SBUCKET; i += 128)
        ((unsigned*)outw)[i] = 0u;
    for (int i = tid; i < 2 * SBUCKET; i += 128)
        ((float*)degw)[i] = 0.0f;
    unsigned lo = bb[k], hi = bb[k + 1];
    unsigned cnt = hi - lo;
    unsigned slice = (cnt + MA - 1) / MA;
    unsigned slo = lo + m * slice;
    unsigned shi = min(slo + slice, hi);
    __syncthreads();

    __half2 (*myout)[SBUCKET] = outw[wv];
    float* mydeg = degw[wv];

    unsigned i0 = slo + tid;
    uint2 z2 = make_uint2(0u, 0u);
    uint2 c0 = z2, c1 = z2, d0 = z2, d1 = z2;
    uint4 zg = make_uint4(0u, 0u, 0u, 0u);
    uint4 g0 = zg, g1 = zg, yg0 = zg, yg1 = zg;
    bool vc0 = i0 < shi,       vc1 = i0 + 128 < shi;
    bool vd0 = i0 + 256 < shi, vd1 = i0 + 384 < shi;
    if (vc0) c0 = w0coef[i0];
    if (vc1) c1 = w0coef[i0 + 128];
    if (vd0) d0 = w0coef[i0 + 256];
    if (vd1) d1 = w0coef[i0 + 384];
    if (vc0) { g0 = yT[c0.x & 0x1FFFFu]; yg0 = yT[n0 + (c0.x >> 17)]; }
    if (vc1) { g1 = yT[c1.x & 0x1FFFFu]; yg1 = yT[n0 + (c1.x >> 17)]; }

    while (__any(vc0)) {
        uint4 h0 = zg, h1 = zg, yh0 = zg, yh1 = zg;
        if (vd0) { h0 = yT[d0.x & 0x1FFFFu]; yh0 = yT[n0 + (d0.x >> 17)]; }
        if (vd1) { h1 = yT[d1.x & 0x1FFFFu]; yh1 = yT[n0 + (d1.x >> 17)]; }
        uint2 e0 = z2, e1 = z2;
        bool ve0 = i0 + 512 < shi, ve1 = i0 + 640 < shi;
        if (ve0) e0 = w0coef[i0 + 512];
        if (ve1) e1 = w0coef[i0 + 640];

#pragma unroll
        for (int half = 0; half < 2; ++half) {
            bool val = half ? vc1 : vc0;
            uint2 cc = half ? c1 : c0;
            uint4 gg = half ? g1 : g0;
            uint4 y0r = half ? yg1 : yg0;
            unsigned s0l = cc.x >> 17;
            // 9-bit ballot grouping of s0l across the wave
            unsigned long long mm = ~0ull;
#pragma unroll
            for (int b = 0; b < 9; ++b) {
                unsigned long long vb = __ballot((s0l >> b) & 1u);
                mm &= ((s0l >> b) & 1u) ? vb : ~vb;
            }
            unsigned rank = __popcll(mm & ((1ull << lane) - 1ull));
            float cf = __uint_as_float(cc.y & 0xFFFF0000u);
            float ge = __uint_as_float(cc.y << 16);
            float q[8];
            {
                const unsigned yw[4] = {y0r.x, y0r.y, y0r.z, y0r.w};
                const unsigned gw[4] = {gg.x, gg.y, gg.z, gg.w};
#pragma unroll
                for (int p = 0; p < 4; ++p) {
                    float ya = __uint_as_float(yw[p] << 16);
                    float yb = __uint_as_float(yw[p] & 0xFFFF0000u);
                    float ga = __uint_as_float(gw[p] << 16);
                    float gb = __uint_as_float(gw[p] & 0xFFFF0000u);
                    q[2 * p]     = cf * fmaxf(ya - ga, 0.0f);
                    q[2 * p + 1] = cf * fmaxf(yb - gb, 0.0f);
                }
            }
            // rank-ordered plain RMW rounds (no atomics)
            unsigned r = 0;
            bool pending = val;
            while (__any(pending && rank >= r ? 1 : 0)) {
                if (pending && rank == r) {
#pragma unroll
                    for (int p = 0; p < 4; ++p) {
                        float2 f = __half22float2(myout[p][s0l]);
                        f.x += q[2 * p];
                        f.y += q[2 * p + 1];
                        myout[p][s0l] = __floats2half2_rn(f.x, f.y);
                    }
                    mydeg[s0l] += ge;
                    pending = false;
                }
                ++r;
            }
        }

        c0 = d0; c1 = d1; d0 = e0; d1 = e1;
        g0 = h0; g1 = h1; yg0 = yh0; yg1 = yh1;
        vc0 = vd0; vc1 = vd1; vd0 = ve0; vd1 = ve1;
        i0 += 256;
    }
    __syncthreads();

    for (int i = tid; i < SBUCKET; i += 128)
        pdegp[(size_t)m * Npad + n0 + i] = degw[0][i] + degw[1][i];
    for (int i = tid; i < 4 * SBUCKET; i += 128) {
        int p = i >> S_LOG;
        int j = i & (SBUCKET - 1);
        float2 a = __half22float2(outw[0][p][j]);
        float2 b = __half22float2(outw[1][p][j]);
        pout[((size_t)m * 4 + p) * Npad + n0 + j] = __floats2half2_rn(a.x + b.x, a.y + b.y);
    }
}

// out[b*N+n] = 1 - (sum_m pout)/deg^2. One thread per node.
__global__ __launch_bounds__(256)
void finalize_kernel(const float* __restrict__ pdegp, const __half2* __restrict__ pout,
                     float* __restrict__ out, int N, int Npad) {
    int n = blockIdx.x * blockDim.x + threadIdx.x;
    if (n >= N) return;
    float d = 0.0f;
#pragma unroll
    for (int m = 0; m < MA; ++m) d += pdegp[(size_t)m * Npad + n];
    float inv = 1.0f / (d * d);
#pragma unroll
    for (int p = 0; p < 4; ++p) {
        float sx = 0.0f, sy = 0.0f;
#pragma unroll
        for (int m = 0; m < MA; ++m) {
            float2 f = __half22float2(pout[((size_t)m * 4 + p) * Npad + n]);
            sx += f.x; sy += f.y;
        }
        out[(size_t)(2 * p) * N + n]     = 1.0f - sx * inv;
        out[(size_t)(2 * p + 1) * N + n] = 1.0f - sy * inv;
    }
}

// ---------------- fallback (R1 path) ----------------

__global__ void fill_one_kernel(float* __restrict__ out, int n) {
    int i = blockIdx.x * blockDim.x + threadIdx.x;
    if (i < n) out[i] = 1.0f;
}

__global__ void zero_kernel(float* __restrict__ p, int n) {
    int i = blockIdx.x * blockDim.x + threadIdx.x;
    if (i < n) p[i] = 0.0f;
}

__global__ void deg_kernel(const float* __restrict__ gea,
                           const int* __restrict__ ei0,
                           float* __restrict__ deg, int E) {
    int e = blockIdx.x * blockDim.x + threadIdx.x;
    if (e < E) atomicAdd(&deg[ei0[e]], gea[e]);
}

__global__ void edge_kernel(const float* __restrict__ y,
                            const float* __restrict__ dw,
                            const int* __restrict__ ei0,
                            const int* __restrict__ ei1,
                            const float* __restrict__ deg,
                            float* __restrict__ out,
                            int E, int N) {
    int e = blockIdx.x * blockDim.x + threadIdx.x;
    if (e >= E) return;
    int s0 = ei0[e];
    int s1 = ei1[e];
    float d = deg[s0];
    float inv = 1.0f / (d * d);
    float sig = 1.0f / (1.0f + __expf(-dw[e]));
    float coef = sqrtf(sig) * inv;
#pragma unroll
    for (int b = 0; b < BATCH; ++b) {
        float y0 = y[(size_t)b * N + s0];
        float y1 = y[(size_t)b * N + s1];
        float gm = coef * fmaxf(y0 - y1, 0.0f);
        if (gm != 0.0f) atomicAdd(&out[(size_t)b * N + s0], -gm);
    }
}

// ---------------- launch ----------------

extern "C" void kernel_launch(void* const* d_in, const int* in_sizes, int n_in,
                              void* d_out, int out_size, void* d_ws, size_t ws_size,
                              hipStream_t stream) {
    const float* y   = (const float*)d_in[0];   // [B,N]
    const float* gea = (const float*)d_in[2];   // [E]
    const float* dw  = (const float*)d_in[3];   // [E]
    const int*   ei  = (const int*)d_in[4];     // [2,E]

    const int E = in_sizes[2];
    const int N = in_sizes[0] / BATCH;
    const int* ei0 = ei;
    const int* ei1 = ei + E;

    const int K = (N + SBUCKET - 1) >> S_LOG;
    const int Npad = K << S_LOG;

    size_t o_yT     = 0;
    size_t o_rcf    = o_yT     + alignup((size_t)Npad * 16);
    size_t o_counts = o_rcf    + alignup((size_t)E * 8);
    size_t o_base   = o_counts + alignup((size_t)KC * CB * 4);
    size_t o_tot    = o_base   + alignup((size_t)KC * CB * 4);
    size_t o_bb     = o_tot    + alignup((size_t)KC * 4);
    size_t o_pdegp  = o_bb     + alignup((size_t)(KC + 1) * 4);
    size_t o_pout   = o_pdegp  + alignup((size_t)MA * Npad * 4);
    size_t need     = o_pout   + alignup((size_t)MA * 4 * Npad * 4);

    if (K <= KC && N <= 131071 && ws_size >= need) {
        char* w = (char*)d_ws;
        uint4*    yT     = (uint4*)(w + o_yT);
        uint2*    w0coef = (uint2*)(w + o_rcf);
        unsigned* counts = (unsigned*)(w + o_counts);
        unsigned* base   = (unsigned*)(w + o_base);
        unsigned* tot    = (unsigned*)(w + o_tot);
        unsigned* bb     = (unsigned*)(w + o_bb);
        float*    pdegp  = (float*)(w + o_pdegp);
        __half2*  pout   = (__half2*)(w + o_pout);

        int tb = (Npad + 255) / 256;
        count_transpose_kernel<<<CB + tb, 256, 0, stream>>>(ei0, counts, y, yT,
                                                            E, N, Npad);
        scanB1_kernel<<<K, 256, 0, stream>>>(counts, base, tot);
        scanC_kernel<<<1, KC, 0, stream>>>(tot, bb, E, K);
        scatter_kernel<<<CB, 256, 0, stream>>>(ei0, ei1, dw, gea, base, bb,
                                               w0coef, E);
        accum_kernel<<<dim3(K, MA), 128, 0, stream>>>(w0coef, bb, yT,
                                                      pdegp, pout, N, Npad);
        finalize_kernel<<<(N + 255) / 256, 256, 0, stream>>>(
            pdegp, pout, (float*)d_out, N, Npad);
    } else {
        float* deg = (float*)d_ws;
        zero_kernel<<<(N + 255) / 256, 256, 0, stream>>>(deg, N);
        fill_one_kernel<<<(out_size + 255) / 256, 256, 0, stream>>>((float*)d_out, out_size);
        deg_kernel<<<(E + 255) / 256, 256, 0, stream>>>(gea, ei0, deg, E);
        edge_kernel<<<(E + 255) / 256, 256, 0, stream>>>(y, dw, ei0, ei1, deg,
                                                         (float*)d_out, E, N);
    }
}

// Round 6
// 159.885 us; speedup vs baseline: 1.0325x; 1.0325x over previous
//
#include <hip/hip_runtime.h>
#include <hip/hip_fp16.h>

#define BATCH 8
#define S_LOG 9
#define SBUCKET 512          // nodes per bucket
#define KC 256               // max buckets (N <= 131071)
#define CB 1024              // blocks for count/scatter
#define TTILE 2048           // edges per sort tile
#define EPT 8                // edges per thread per tile (contiguous)
#define MA 8                 // accum sub-blocks per bucket

static inline size_t alignup(size_t x) { return (x + 255) & ~(size_t)255; }

__device__ __forceinline__ unsigned bf16hi(unsigned u) {
    // fp32 -> bf16 (rne), returned in LOW 16 bits
    return (u + 0x7FFFu + ((u >> 16) & 1u)) >> 16;
}

__device__ __forceinline__ int aligned_chunk(int E) {
    return (((E + CB - 1) / CB) + 15) & ~15;    // 16-elem aligned => 64B
}

// ---------------- pipeline kernels ----------------

// fused: blocks [0,CB) bucket-count (int4 loads, uint LDS atomics); blocks [CB,...)
// transpose y -> yT[node] = 8 bf16 (uint4)
__global__ __launch_bounds__(256)
void count_transpose_kernel(const int* __restrict__ ei0, unsigned* __restrict__ counts,
                            const float* __restrict__ y, uint4* __restrict__ yT,
                            int E, int N, int Npad) {
    __shared__ unsigned cnt[KC];
    int tid = threadIdx.x;
    if (blockIdx.x >= CB) {
        int n = (blockIdx.x - CB) * 256 + tid;
        if (n < Npad) {
            uint4 o = make_uint4(0u, 0u, 0u, 0u);
            if (n < N) {
                unsigned p[8];
#pragma unroll
                for (int b = 0; b < BATCH; ++b)
                    p[b] = bf16hi(__float_as_uint(y[(size_t)b * N + n]));
                o = make_uint4(p[0] | (p[1] << 16), p[2] | (p[3] << 16),
                               p[4] | (p[5] << 16), p[6] | (p[7] << 16));
            }
            yT[n] = o;
        }
        return;
    }
    cnt[tid] = 0;
    __syncthreads();
    int chunk = aligned_chunk(E);
    int lo = blockIdx.x * chunk;
    int hi = min(lo + chunk, E);
    for (int bi = lo; bi < hi; bi += 1024) {
        int idx = bi + tid * 4;
        if (idx + 4 <= hi) {
            int4 v = *(const int4*)(ei0 + idx);
            atomicAdd(&cnt[(unsigned)v.x >> S_LOG], 1u);
            atomicAdd(&cnt[(unsigned)v.y >> S_LOG], 1u);
            atomicAdd(&cnt[(unsigned)v.z >> S_LOG], 1u);
            atomicAdd(&cnt[(unsigned)v.w >> S_LOG], 1u);
        } else {
#pragma unroll
            for (int j = 0; j < 4; ++j) {
                int i2 = idx + j;
                if (i2 < hi) atomicAdd(&cnt[(unsigned)ei0[i2] >> S_LOG], 1u);
            }
        }
    }
    __syncthreads();
    counts[(size_t)tid * CB + blockIdx.x] = cnt[tid];   // [bucket][block]
}

// scanB1: one block per bucket — local exclusive prefix of counts[k][0..CB) -> base,
// and bucket total -> tot[k].
__global__ __launch_bounds__(256)
void scanB1_kernel(const unsigned* __restrict__ counts, unsigned* __restrict__ base,
                   unsigned* __restrict__ tot) {
    __shared__ unsigned ssum[256];
    int k = blockIdx.x, tid = threadIdx.x;
    const uint4* row4 = (const uint4*)(counts + (size_t)k * CB);
    uint4 v = row4[tid];
    unsigned lsum = v.x + v.y + v.z + v.w;
    ssum[tid] = lsum;
    __syncthreads();
    for (int off = 1; off < 256; off <<= 1) {
        unsigned u = ssum[tid];
        unsigned a = (tid >= off) ? ssum[tid - off] : 0u;
        __syncthreads();
        ssum[tid] = u + a;
        __syncthreads();
    }
    unsigned ex = ssum[tid] - lsum;
    if (tid == 255) tot[k] = ssum[255];
    uint4 o;
    o.x = ex;
    o.y = ex + v.x;
    o.z = o.y + v.y;
    o.w = o.z + v.z;
    ((uint4*)(base + (size_t)k * CB))[tid] = o;
}

// scanC: one block — exclusive scan of bucket totals -> bb[0..KC], bb[KC]=E
__global__ void scanC_kernel(const unsigned* __restrict__ tot,
                             unsigned* __restrict__ bb, int E, int K) {
    __shared__ unsigned sb[KC];
    int t = threadIdx.x;
    unsigned v = (t < K) ? tot[t] : 0u;
    sb[t] = v;
    __syncthreads();
    for (int off = 1; off < KC; off <<= 1) {
        unsigned u = sb[t];
        unsigned a = (t >= off) ? sb[t - off] : 0u;
        __syncthreads();
        sb[t] = u + a;
        __syncthreads();
    }
    bb[t] = sb[t] - v;
    if (t == KC - 1) bb[KC] = (unsigned)E;
}

// scatter: bucket-sort edges into w0coef records (uint LDS atomics — cheap).
// Per-thread CONTIGUOUS EPT elements => int4/float4 vector loads.
// record: .x = s1 | s0l<<17 ; .y = bf16(coef)<<16 | bf16(gea)
__global__ __launch_bounds__(256)
void scatter_kernel(const int* __restrict__ ei0, const int* __restrict__ ei1,
                    const float* __restrict__ dw, const float* __restrict__ gea,
                    const unsigned* __restrict__ base, const unsigned* __restrict__ bb,
                    uint2* __restrict__ w0coef, int E) {
    __shared__ unsigned cursor[KC];
    __shared__ unsigned h[KC];
    __shared__ unsigned tstart[KC];
    __shared__ unsigned wsum[4];
    __shared__ uint2 srec[TTILE];            // 16 KB
    __shared__ unsigned char skey[TTILE];    // 2 KB
    int tid = threadIdx.x;
    cursor[tid] = base[(size_t)tid * CB + blockIdx.x] + bb[tid];
    int chunk = aligned_chunk(E);
    int lo = blockIdx.x * chunk;
    int hi = min(lo + chunk, E);
    __syncthreads();

    for (int tileLo = lo; tileLo < hi; tileLo += TTILE) {
        int tn = min(TTILE, hi - tileLo);
        h[tid] = 0;
        __syncthreads();

        int base_off = tid * EPT;
        unsigned k_r[EPT], w0_r[EPT], pk_r[EPT], rk_r[EPT];
        int s0a[EPT], s1a[EPT];
        float dwa[EPT], gea_a[EPT];
        bool anyv = base_off < tn;
        if (base_off + EPT <= tn) {
            // vector loads (tileLo 16-aligned, base_off multiple of 8)
            const int4* p0 = (const int4*)(ei0 + tileLo + base_off);
            const int4* p1 = (const int4*)(ei1 + tileLo + base_off);
            const float4* pd = (const float4*)(dw + tileLo + base_off);
            const float4* pg = (const float4*)(gea + tileLo + base_off);
            int4 a0 = p0[0], a1 = p0[1];
            int4 b0 = p1[0], b1 = p1[1];
            float4 d0 = pd[0], d1 = pd[1];
            float4 g0 = pg[0], g1 = pg[1];
            s0a[0]=a0.x; s0a[1]=a0.y; s0a[2]=a0.z; s0a[3]=a0.w;
            s0a[4]=a1.x; s0a[5]=a1.y; s0a[6]=a1.z; s0a[7]=a1.w;
            s1a[0]=b0.x; s1a[1]=b0.y; s1a[2]=b0.z; s1a[3]=b0.w;
            s1a[4]=b1.x; s1a[5]=b1.y; s1a[6]=b1.z; s1a[7]=b1.w;
            dwa[0]=d0.x; dwa[1]=d0.y; dwa[2]=d0.z; dwa[3]=d0.w;
            dwa[4]=d1.x; dwa[5]=d1.y; dwa[6]=d1.z; dwa[7]=d1.w;
            gea_a[0]=g0.x; gea_a[1]=g0.y; gea_a[2]=g0.z; gea_a[3]=g0.w;
            gea_a[4]=g1.x; gea_a[5]=g1.y; gea_a[6]=g1.z; gea_a[7]=g1.w;
#pragma unroll
            for (int j = 0; j < EPT; ++j) k_r[j] = 0u;   // mark all valid below
#pragma unroll
            for (int j = 0; j < EPT; ++j) {
                unsigned k = (unsigned)s0a[j] >> S_LOG;
                unsigned s0l = (unsigned)(s0a[j] & (SBUCKET - 1));
                k_r[j] = k;
                w0_r[j] = (unsigned)s1a[j] | (s0l << 17);
                float sig = 1.0f / (1.0f + __expf(-dwa[j]));
                pk_r[j] = (bf16hi(__float_as_uint(sqrtf(sig))) << 16) |
                          bf16hi(__float_as_uint(gea_a[j]));
            }
#pragma unroll
            for (int j = 0; j < EPT; ++j)
                rk_r[j] = atomicAdd(&h[k_r[j]], 1u);
        } else {
#pragma unroll
            for (int j = 0; j < EPT; ++j) {
                int off = base_off + j;
                k_r[j] = 0xFFFFFFFFu;
                if (off < tn) {
                    int i = tileLo + off;
                    int s0v = ei0[i];
                    int s1v = ei1[i];
                    unsigned k = (unsigned)s0v >> S_LOG;
                    unsigned s0l = (unsigned)(s0v & (SBUCKET - 1));
                    k_r[j] = k;
                    w0_r[j] = (unsigned)s1v | (s0l << 17);
                    float sig = 1.0f / (1.0f + __expf(-dw[i]));
                    pk_r[j] = (bf16hi(__float_as_uint(sqrtf(sig))) << 16) |
                              bf16hi(__float_as_uint(gea[i]));
                }
            }
#pragma unroll
            for (int j = 0; j < EPT; ++j)
                if (k_r[j] != 0xFFFFFFFFu) rk_r[j] = atomicAdd(&h[k_r[j]], 1u);
        }
        bool fullv = base_off + EPT <= tn;
        __syncthreads();

        // exclusive scan of h[256] via wave shuffles
        unsigned hv = h[tid];
        unsigned v = hv;
        unsigned lane = tid & 63;
        unsigned wv = tid >> 6;
#pragma unroll
        for (int off = 1; off < 64; off <<= 1) {
            unsigned t = __shfl_up(v, off, 64);
            if (lane >= off) v += t;
        }
        if (lane == 63) wsum[wv] = v;
        __syncthreads();
        unsigned addv = 0;
#pragma unroll
        for (unsigned w = 0; w < 4; ++w)
            if (w < wv) addv += wsum[w];
        tstart[tid] = v + addv - hv;
        __syncthreads();

        if (fullv) {
#pragma unroll
            for (int j = 0; j < EPT; ++j) {
                unsigned slot = tstart[k_r[j]] + rk_r[j];
                srec[slot] = make_uint2(w0_r[j], pk_r[j]);
                skey[slot] = (unsigned char)k_r[j];
            }
        } else if (anyv) {
#pragma unroll
            for (int j = 0; j < EPT; ++j)
                if (k_r[j] != 0xFFFFFFFFu) {
                    unsigned slot = tstart[k_r[j]] + rk_r[j];
                    srec[slot] = make_uint2(w0_r[j], pk_r[j]);
                    skey[slot] = (unsigned char)k_r[j];
                }
        }
        __syncthreads();

        for (int i = tid; i < tn; i += 256) {
            uint2 u = srec[i];
            unsigned k = skey[i];
            unsigned pos = cursor[k] + ((unsigned)i - tstart[k]);
            w0coef[pos] = u;
        }
        __syncthreads();
        cursor[tid] += h[tid];
        __syncthreads();
    }
}

// main accumulation: grid (K, MA), 128 threads (2 waves) — NO LDS f32 atomics
// (measured R1: ds_add_f32 is ~3.7 cy/lane -> 4x slower than this scheme).
// Per-wave private accumulators packed as uint4 = 4 half2 (8 batches) per node
// so each duplicate-round is ds_read_b128+ds_read_b32+ds_write_b128+ds_write_b32
// (4 DS instr) instead of 10 — accum is LDS-issue-bound (R5 analysis).
// Duplicates resolved by 9-bit ballot grouping + rank-ordered RMW rounds.
__global__ __launch_bounds__(128)
void accum_kernel(const uint2* __restrict__ w0coef, const unsigned* __restrict__ bb,
                  const uint4* __restrict__ yT,
                  float* __restrict__ pdegp, __half2* __restrict__ pout,
                  int N, int Npad) {
    __shared__ uint4  outw[2][SBUCKET];           // 16 KB: [wave][node] = 4x half2
    __shared__ float  degw[2][SBUCKET];           // 4 KB:  [wave][node]
    int k = blockIdx.x, m = blockIdx.y, tid = threadIdx.x;
    int n0 = k << S_LOG;
    unsigned lane = tid & 63;
    unsigned wv = tid >> 6;

    uint4 z4i = make_uint4(0u, 0u, 0u, 0u);
    for (int i = tid; i < 2 * SBUCKET; i += 128)
        ((uint4*)outw)[i] = z4i;
    for (int i = tid; i < 2 * SBUCKET; i += 128)
        ((float*)degw)[i] = 0.0f;
    unsigned lo = bb[k], hi = bb[k + 1];
    unsigned cnt = hi - lo;
    unsigned slice = (cnt + MA - 1) / MA;
    unsigned slo = lo + m * slice;
    unsigned shi = min(slo + slice, hi);
    __syncthreads();

    uint4* myout = outw[wv];
    float* mydeg = degw[wv];

    unsigned i0 = slo + tid;
    uint2 z2 = make_uint2(0u, 0u);
    uint2 c0 = z2, c1 = z2, d0 = z2, d1 = z2;
    uint4 zg = make_uint4(0u, 0u, 0u, 0u);
    uint4 g0 = zg, g1 = zg, yg0 = zg, yg1 = zg;
    bool vc0 = i0 < shi,       vc1 = i0 + 128 < shi;
    bool vd0 = i0 + 256 < shi, vd1 = i0 + 384 < shi;
    if (vc0) c0 = w0coef[i0];
    if (vc1) c1 = w0coef[i0 + 128];
    if (vd0) d0 = w0coef[i0 + 256];
    if (vd1) d1 = w0coef[i0 + 384];
    if (vc0) { g0 = yT[c0.x & 0x1FFFFu]; yg0 = yT[n0 + (c0.x >> 17)]; }
    if (vc1) { g1 = yT[c1.x & 0x1FFFFu]; yg1 = yT[n0 + (c1.x >> 17)]; }

    while (__any(vc0)) {
        uint4 h0 = zg, h1 = zg, yh0 = zg, yh1 = zg;
        if (vd0) { h0 = yT[d0.x & 0x1FFFFu]; yh0 = yT[n0 + (d0.x >> 17)]; }
        if (vd1) { h1 = yT[d1.x & 0x1FFFFu]; yh1 = yT[n0 + (d1.x >> 17)]; }
        uint2 e0 = z2, e1 = z2;
        bool ve0 = i0 + 512 < shi, ve1 = i0 + 640 < shi;
        if (ve0) e0 = w0coef[i0 + 512];
        if (ve1) e1 = w0coef[i0 + 640];

#pragma unroll
        for (int half = 0; half < 2; ++half) {
            bool val = half ? vc1 : vc0;
            uint2 cc = half ? c1 : c0;
            uint4 gg = half ? g1 : g0;
            uint4 y0r = half ? yg1 : yg0;
            unsigned s0l = cc.x >> 17;
            // 9-bit ballot grouping of s0l across the wave
            unsigned long long mm = ~0ull;
#pragma unroll
            for (int b = 0; b < 9; ++b) {
                unsigned long long vb = __ballot((s0l >> b) & 1u);
                mm &= ((s0l >> b) & 1u) ? vb : ~vb;
            }
            unsigned rank = __popcll(mm & ((1ull << lane) - 1ull));
            float cf = __uint_as_float(cc.y & 0xFFFF0000u);
            float ge = __uint_as_float(cc.y << 16);
            float q[8];
            {
                const unsigned yw[4] = {y0r.x, y0r.y, y0r.z, y0r.w};
                const unsigned gw[4] = {gg.x, gg.y, gg.z, gg.w};
#pragma unroll
                for (int p = 0; p < 4; ++p) {
                    float ya = __uint_as_float(yw[p] << 16);
                    float yb = __uint_as_float(yw[p] & 0xFFFF0000u);
                    float ga = __uint_as_float(gw[p] << 16);
                    float gb = __uint_as_float(gw[p] & 0xFFFF0000u);
                    q[2 * p]     = cf * fmaxf(ya - ga, 0.0f);
                    q[2 * p + 1] = cf * fmaxf(yb - gb, 0.0f);
                }
            }
            // rank-ordered plain RMW rounds (no atomics), b128-packed cell
            unsigned r = 0;
            bool pending = val;
            while (__any(pending && rank >= r ? 1 : 0)) {
                if (pending && rank == r) {
                    uint4 cur = myout[s0l];           // ds_read_b128
                    unsigned cw[4] = {cur.x, cur.y, cur.z, cur.w};
#pragma unroll
                    for (int p = 0; p < 4; ++p) {
                        __half2 hv = *reinterpret_cast<__half2*>(&cw[p]);
                        float2 f = __half22float2(hv);
                        f.x += q[2 * p];
                        f.y += q[2 * p + 1];
                        hv = __floats2half2_rn(f.x, f.y);
                        cw[p] = *reinterpret_cast<unsigned*>(&hv);
                    }
                    myout[s0l] = make_uint4(cw[0], cw[1], cw[2], cw[3]);  // ds_write_b128
                    mydeg[s0l] += ge;
                    pending = false;
                }
                ++r;
            }
        }

        c0 = d0; c1 = d1; d0 = e0; d1 = e1;
        g0 = h0; g1 = h1; yg0 = yh0; yg1 = yh1;
        vc0 = vd0; vc1 = vd1; vd0 = ve0; vd1 = ve1;
        i0 += 256;
    }
    __syncthreads();

    for (int i = tid; i < SBUCKET; i += 128)
        pdegp[(size_t)m * Npad + n0 + i] = degw[0][i] + degw[1][i];
    for (int j = tid; j < SBUCKET; j += 128) {
        uint4 a = outw[0][j];
        uint4 b = outw[1][j];
        unsigned aw[4] = {a.x, a.y, a.z, a.w};
        unsigned bw[4] = {b.x, b.y, b.z, b.w};
#pragma unroll
        for (int p = 0; p < 4; ++p) {
            float2 fa = __half22float2(*reinterpret_cast<__half2*>(&aw[p]));
            float2 fb = __half22float2(*reinterpret_cast<__half2*>(&bw[p]));
            pout[((size_t)m * 4 + p) * Npad + n0 + j] =
                __floats2half2_rn(fa.x + fb.x, fa.y + fb.y);
        }
    }
}

// out[b*N+n] = 1 - (sum_m pout)/deg^2. One thread per node.
__global__ __launch_bounds__(256)
void finalize_kernel(const float* __restrict__ pdegp, const __half2* __restrict__ pout,
                     float* __restrict__ out, int N, int Npad) {
    int n = blockIdx.x * blockDim.x + threadIdx.x;
    if (n >= N) return;
    float d = 0.0f;
#pragma unroll
    for (int m = 0; m < MA; ++m) d += pdegp[(size_t)m * Npad + n];
    float inv = 1.0f / (d * d);
#pragma unroll
    for (int p = 0; p < 4; ++p) {
        float sx = 0.0f, sy = 0.0f;
#pragma unroll
        for (int m = 0; m < MA; ++m) {
            float2 f = __half22float2(pout[((size_t)m * 4 + p) * Npad + n]);
            sx += f.x; sy += f.y;
        }
        out[(size_t)(2 * p) * N + n]     = 1.0f - sx * inv;
        out[(size_t)(2 * p + 1) * N + n] = 1.0f - sy * inv;
    }
}

// ---------------- fallback (R1 path) ----------------

__global__ void fill_one_kernel(float* __restrict__ out, int n) {
    int i = blockIdx.x * blockDim.x + threadIdx.x;
    if (i < n) out[i] = 1.0f;
}

__global__ void zero_kernel(float* __restrict__ p, int n) {
    int i = blockIdx.x * blockDim.x + threadIdx.x;
    if (i < n) p[i] = 0.0f;
}

__global__ void deg_kernel(const float* __restrict__ gea,
                           const int* __restrict__ ei0,
                           float* __restrict__ deg, int E) {
    int e = blockIdx.x * blockDim.x + threadIdx.x;
    if (e < E) atomicAdd(&deg[ei0[e]], gea[e]);
}

__global__ void edge_kernel(const float* __restrict__ y,
                            const float* __restrict__ dw,
                            const int* __restrict__ ei0,
                            const int* __restrict__ ei1,
                            const float* __restrict__ deg,
                            float* __restrict__ out,
                            int E, int N) {
    int e = blockIdx.x * blockDim.x + threadIdx.x;
    if (e >= E) return;
    int s0 = ei0[e];
    int s1 = ei1[e];
    float d = deg[s0];
    float inv = 1.0f / (d * d);
    float sig = 1.0f / (1.0f + __expf(-dw[e]));
    float coef = sqrtf(sig) * inv;
#pragma unroll
    for (int b = 0; b < BATCH; ++b) {
        float y0 = y[(size_t)b * N + s0];
        float y1 = y[(size_t)b * N + s1];
        float gm = coef * fmaxf(y0 - y1, 0.0f);
        if (gm != 0.0f) atomicAdd(&out[(size_t)b * N + s0], -gm);
    }
}

// ---------------- launch ----------------

extern "C" void kernel_launch(void* const* d_in, const int* in_sizes, int n_in,
                              void* d_out, int out_size, void* d_ws, size_t ws_size,
                              hipStream_t stream) {
    const float* y   = (const float*)d_in[0];   // [B,N]
    const float* gea = (const float*)d_in[2];   // [E]
    const float* dw  = (const float*)d_in[3];   // [E]
    const int*   ei  = (const int*)d_in[4];     // [2,E]

    const int E = in_sizes[2];
    const int N = in_sizes[0] / BATCH;
    const int* ei0 = ei;
    const int* ei1 = ei + E;

    const int K = (N + SBUCKET - 1) >> S_LOG;
    const int Npad = K << S_LOG;

    size_t o_yT     = 0;
    size_t o_rcf    = o_yT     + alignup((size_t)Npad * 16);
    size_t o_counts = o_rcf    + alignup((size_t)E * 8);
    size_t o_base   = o_counts + alignup((size_t)KC * CB * 4);
    size_t o_tot    = o_base   + alignup((size_t)KC * CB * 4);
    size_t o_bb     = o_tot    + alignup((size_t)KC * 4);
    size_t o_pdegp  = o_bb     + alignup((size_t)(KC + 1) * 4);
    size_t o_pout   = o_pdegp  + alignup((size_t)MA * Npad * 4);
    size_t need     = o_pout   + alignup((size_t)MA * 4 * Npad * 4);

    if (K <= KC && N <= 131071 && ws_size >= need) {
        char* w = (char*)d_ws;
        uint4*    yT     = (uint4*)(w + o_yT);
        uint2*    w0coef = (uint2*)(w + o_rcf);
        unsigned* counts = (unsigned*)(w + o_counts);
        unsigned* base   = (unsigned*)(w + o_base);
        unsigned* tot    = (unsigned*)(w + o_tot);
        unsigned* bb     = (unsigned*)(w + o_bb);
        float*    pdegp  = (float*)(w + o_pdegp);
        __half2*  pout   = (__half2*)(w + o_pout);

        int tb = (Npad + 255) / 256;
        count_transpose_kernel<<<CB + tb, 256, 0, stream>>>(ei0, counts, y, yT,
                                                            E, N, Npad);
        scanB1_kernel<<<K, 256, 0, stream>>>(counts, base, tot);
        scanC_kernel<<<1, KC, 0, stream>>>(tot, bb, E, K);
        scatter_kernel<<<CB, 256, 0, stream>>>(ei0, ei1, dw, gea, base, bb,
                                               w0coef, E);
        accum_kernel<<<dim3(K, MA), 128, 0, stream>>>(w0coef, bb, yT,
                                                      pdegp, pout, N, Npad);
        finalize_kernel<<<(N + 255) / 256, 256, 0, stream>>>(
            pdegp, pout, (float*)d_out, N, Npad);
    } else {
        float* deg = (float*)d_ws;
        zero_kernel<<<(N + 255) / 256, 256, 0, stream>>>(deg, N);
        fill_one_kernel<<<(out_size + 255) / 256, 256, 0, stream>>>((float*)d_out, out_size);
        deg_kernel<<<(E + 255) / 256, 256, 0, stream>>>(gea, ei0, deg, E);
        edge_kernel<<<(E + 255) / 256, 256, 0, stream>>>(y, dw, ei0, ei1, deg,
                                                         (float*)d_out, E, N);
    }
}

// Round 7
// 157.311 us; speedup vs baseline: 1.0494x; 1.0164x over previous
//
#include <hip/hip_runtime.h>
#include <hip/hip_fp16.h>

#define BATCH 8
#define S_LOG 9
#define SBUCKET 512          // nodes per bucket
#define KC 256               // max buckets (N <= 131071)
#define CB 1024              // blocks for count/scatter
#define TTILE 2048           // edges per sort tile
#define EPT 8                // edges per thread per tile (contiguous)
#define MA 6                 // accum sub-blocks per bucket (196*6=1176 <= 1536 slots @6/CU)
#define QCAP 384             // per-wave overflow queue capacity

static inline size_t alignup(size_t x) { return (x + 255) & ~(size_t)255; }

__device__ __forceinline__ unsigned bf16hi(unsigned u) {
    // fp32 -> bf16 (rne), returned in LOW 16 bits
    return (u + 0x7FFFu + ((u >> 16) & 1u)) >> 16;
}

__device__ __forceinline__ int aligned_chunk(int E) {
    return (((E + CB - 1) / CB) + 15) & ~15;    // 16-elem aligned => 64B
}

// ---------------- pipeline kernels ----------------

// fused: blocks [0,CB) bucket-count (int4 loads, uint LDS atomics); blocks [CB,...)
// transpose y -> yT[node] = 8 bf16 (uint4)
__global__ __launch_bounds__(256)
void count_transpose_kernel(const int* __restrict__ ei0, unsigned* __restrict__ counts,
                            const float* __restrict__ y, uint4* __restrict__ yT,
                            int E, int N, int Npad) {
    __shared__ unsigned cnt[KC];
    int tid = threadIdx.x;
    if (blockIdx.x >= CB) {
        int n = (blockIdx.x - CB) * 256 + tid;
        if (n < Npad) {
            uint4 o = make_uint4(0u, 0u, 0u, 0u);
            if (n < N) {
                unsigned p[8];
#pragma unroll
                for (int b = 0; b < BATCH; ++b)
                    p[b] = bf16hi(__float_as_uint(y[(size_t)b * N + n]));
                o = make_uint4(p[0] | (p[1] << 16), p[2] | (p[3] << 16),
                               p[4] | (p[5] << 16), p[6] | (p[7] << 16));
            }
            yT[n] = o;
        }
        return;
    }
    cnt[tid] = 0;
    __syncthreads();
    int chunk = aligned_chunk(E);
    int lo = blockIdx.x * chunk;
    int hi = min(lo + chunk, E);
    for (int bi = lo; bi < hi; bi += 1024) {
        int idx = bi + tid * 4;
        if (idx + 4 <= hi) {
            int4 v = *(const int4*)(ei0 + idx);
            atomicAdd(&cnt[(unsigned)v.x >> S_LOG], 1u);
            atomicAdd(&cnt[(unsigned)v.y >> S_LOG], 1u);
            atomicAdd(&cnt[(unsigned)v.z >> S_LOG], 1u);
            atomicAdd(&cnt[(unsigned)v.w >> S_LOG], 1u);
        } else {
#pragma unroll
            for (int j = 0; j < 4; ++j) {
                int i2 = idx + j;
                if (i2 < hi) atomicAdd(&cnt[(unsigned)ei0[i2] >> S_LOG], 1u);
            }
        }
    }
    __syncthreads();
    counts[(size_t)tid * CB + blockIdx.x] = cnt[tid];   // [bucket][block]
}

// scanB1: one block per bucket — local exclusive prefix of counts[k][0..CB) -> base,
// and bucket total -> tot[k].
__global__ __launch_bounds__(256)
void scanB1_kernel(const unsigned* __restrict__ counts, unsigned* __restrict__ base,
                   unsigned* __restrict__ tot) {
    __shared__ unsigned ssum[256];
    int k = blockIdx.x, tid = threadIdx.x;
    const uint4* row4 = (const uint4*)(counts + (size_t)k * CB);
    uint4 v = row4[tid];
    unsigned lsum = v.x + v.y + v.z + v.w;
    ssum[tid] = lsum;
    __syncthreads();
    for (int off = 1; off < 256; off <<= 1) {
        unsigned u = ssum[tid];
        unsigned a = (tid >= off) ? ssum[tid - off] : 0u;
        __syncthreads();
        ssum[tid] = u + a;
        __syncthreads();
    }
    unsigned ex = ssum[tid] - lsum;
    if (tid == 255) tot[k] = ssum[255];
    uint4 o;
    o.x = ex;
    o.y = ex + v.x;
    o.z = o.y + v.y;
    o.w = o.z + v.z;
    ((uint4*)(base + (size_t)k * CB))[tid] = o;
}

// scanC: one block — exclusive scan of bucket totals -> bb[0..KC], bb[KC]=E
__global__ void scanC_kernel(const unsigned* __restrict__ tot,
                             unsigned* __restrict__ bb, int E, int K) {
    __shared__ unsigned sb[KC];
    int t = threadIdx.x;
    unsigned v = (t < K) ? tot[t] : 0u;
    sb[t] = v;
    __syncthreads();
    for (int off = 1; off < KC; off <<= 1) {
        unsigned u = sb[t];
        unsigned a = (t >= off) ? sb[t - off] : 0u;
        __syncthreads();
        sb[t] = u + a;
        __syncthreads();
    }
    bb[t] = sb[t] - v;
    if (t == KC - 1) bb[KC] = (unsigned)E;
}

// scatter: bucket-sort edges into w0coef records (uint LDS atomics — cheap).
// Per-thread CONTIGUOUS EPT elements => int4/float4 vector loads.
// record: .x = s1 | s0l<<17 ; .y = bf16(coef)<<16 | bf16(gea)
__global__ __launch_bounds__(256)
void scatter_kernel(const int* __restrict__ ei0, const int* __restrict__ ei1,
                    const float* __restrict__ dw, const float* __restrict__ gea,
                    const unsigned* __restrict__ base, const unsigned* __restrict__ bb,
                    uint2* __restrict__ w0coef, int E) {
    __shared__ unsigned cursor[KC];
    __shared__ unsigned h[KC];
    __shared__ unsigned tstart[KC];
    __shared__ unsigned wsum[4];
    __shared__ uint2 srec[TTILE];            // 16 KB
    __shared__ unsigned char skey[TTILE];    // 2 KB
    int tid = threadIdx.x;
    cursor[tid] = base[(size_t)tid * CB + blockIdx.x] + bb[tid];
    int chunk = aligned_chunk(E);
    int lo = blockIdx.x * chunk;
    int hi = min(lo + chunk, E);
    __syncthreads();

    for (int tileLo = lo; tileLo < hi; tileLo += TTILE) {
        int tn = min(TTILE, hi - tileLo);
        h[tid] = 0;
        __syncthreads();

        int base_off = tid * EPT;
        unsigned k_r[EPT], w0_r[EPT], pk_r[EPT], rk_r[EPT];
        int s0a[EPT], s1a[EPT];
        float dwa[EPT], gea_a[EPT];
        bool anyv = base_off < tn;
        if (base_off + EPT <= tn) {
            // vector loads (tileLo 16-aligned, base_off multiple of 8)
            const int4* p0 = (const int4*)(ei0 + tileLo + base_off);
            const int4* p1 = (const int4*)(ei1 + tileLo + base_off);
            const float4* pd = (const float4*)(dw + tileLo + base_off);
            const float4* pg = (const float4*)(gea + tileLo + base_off);
            int4 a0 = p0[0], a1 = p0[1];
            int4 b0 = p1[0], b1 = p1[1];
            float4 d0 = pd[0], d1 = pd[1];
            float4 g0 = pg[0], g1 = pg[1];
            s0a[0]=a0.x; s0a[1]=a0.y; s0a[2]=a0.z; s0a[3]=a0.w;
            s0a[4]=a1.x; s0a[5]=a1.y; s0a[6]=a1.z; s0a[7]=a1.w;
            s1a[0]=b0.x; s1a[1]=b0.y; s1a[2]=b0.z; s1a[3]=b0.w;
            s1a[4]=b1.x; s1a[5]=b1.y; s1a[6]=b1.z; s1a[7]=b1.w;
            dwa[0]=d0.x; dwa[1]=d0.y; dwa[2]=d0.z; dwa[3]=d0.w;
            dwa[4]=d1.x; dwa[5]=d1.y; dwa[6]=d1.z; dwa[7]=d1.w;
            gea_a[0]=g0.x; gea_a[1]=g0.y; gea_a[2]=g0.z; gea_a[3]=g0.w;
            gea_a[4]=g1.x; gea_a[5]=g1.y; gea_a[6]=g1.z; gea_a[7]=g1.w;
#pragma unroll
            for (int j = 0; j < EPT; ++j) k_r[j] = 0u;   // mark all valid below
#pragma unroll
            for (int j = 0; j < EPT; ++j) {
                unsigned k = (unsigned)s0a[j] >> S_LOG;
                unsigned s0l = (unsigned)(s0a[j] & (SBUCKET - 1));
                k_r[j] = k;
                w0_r[j] = (unsigned)s1a[j] | (s0l << 17);
                float sig = 1.0f / (1.0f + __expf(-dwa[j]));
                pk_r[j] = (bf16hi(__float_as_uint(sqrtf(sig))) << 16) |
                          bf16hi(__float_as_uint(gea_a[j]));
            }
#pragma unroll
            for (int j = 0; j < EPT; ++j)
                rk_r[j] = atomicAdd(&h[k_r[j]], 1u);
        } else {
#pragma unroll
            for (int j = 0; j < EPT; ++j) {
                int off = base_off + j;
                k_r[j] = 0xFFFFFFFFu;
                if (off < tn) {
                    int i = tileLo + off;
                    int s0v = ei0[i];
                    int s1v = ei1[i];
                    unsigned k = (unsigned)s0v >> S_LOG;
                    unsigned s0l = (unsigned)(s0v & (SBUCKET - 1));
                    k_r[j] = k;
                    w0_r[j] = (unsigned)s1v | (s0l << 17);
                    float sig = 1.0f / (1.0f + __expf(-dw[i]));
                    pk_r[j] = (bf16hi(__float_as_uint(sqrtf(sig))) << 16) |
                              bf16hi(__float_as_uint(gea[i]));
                }
            }
#pragma unroll
            for (int j = 0; j < EPT; ++j)
                if (k_r[j] != 0xFFFFFFFFu) rk_r[j] = atomicAdd(&h[k_r[j]], 1u);
        }
        bool fullv = base_off + EPT <= tn;
        __syncthreads();

        // exclusive scan of h[256] via wave shuffles
        unsigned hv = h[tid];
        unsigned v = hv;
        unsigned lane = tid & 63;
        unsigned wv = tid >> 6;
#pragma unroll
        for (int off = 1; off < 64; off <<= 1) {
            unsigned t = __shfl_up(v, off, 64);
            if (lane >= off) v += t;
        }
        if (lane == 63) wsum[wv] = v;
        __syncthreads();
        unsigned addv = 0;
#pragma unroll
        for (unsigned w = 0; w < 4; ++w)
            if (w < wv) addv += wsum[w];
        tstart[tid] = v + addv - hv;
        __syncthreads();

        if (fullv) {
#pragma unroll
            for (int j = 0; j < EPT; ++j) {
                unsigned slot = tstart[k_r[j]] + rk_r[j];
                srec[slot] = make_uint2(w0_r[j], pk_r[j]);
                skey[slot] = (unsigned char)k_r[j];
            }
        } else if (anyv) {
#pragma unroll
            for (int j = 0; j < EPT; ++j)
                if (k_r[j] != 0xFFFFFFFFu) {
                    unsigned slot = tstart[k_r[j]] + rk_r[j];
                    srec[slot] = make_uint2(w0_r[j], pk_r[j]);
                    skey[slot] = (unsigned char)k_r[j];
                }
        }
        __syncthreads();

        for (int i = tid; i < tn; i += 256) {
            uint2 u = srec[i];
            unsigned k = skey[i];
            unsigned pos = cursor[k] + ((unsigned)i - tstart[k]);
            w0coef[pos] = u;
        }
        __syncthreads();
        cursor[tid] += h[tid];
        __syncthreads();
    }
}

// full duplicate-safe RMW (ballot grouping + rank-ordered rounds) — used only
// for overflow-queue entries (~8% of records). Gathers yT internally.
__device__ __forceinline__ void process_dups(uint4* myout, float* mydeg,
                                             const uint4* __restrict__ yT, int n0,
                                             uint2 cc, bool val, unsigned lane) {
    unsigned s0l = cc.x >> 17;
    unsigned long long mm = ~0ull;
#pragma unroll
    for (int b = 0; b < 9; ++b) {
        unsigned long long vb = __ballot((s0l >> b) & 1u);
        mm &= ((s0l >> b) & 1u) ? vb : ~vb;
    }
    {
        unsigned long long vb = __ballot(val ? 1 : 0);
        mm &= val ? vb : ~vb;
    }
    unsigned rank = __popcll(mm & ((1ull << lane) - 1ull));
    uint4 zg = make_uint4(0u, 0u, 0u, 0u);
    uint4 gg = zg, y0r = zg;
    if (val) { gg = yT[cc.x & 0x1FFFFu]; y0r = yT[n0 + s0l]; }
    float cf = __uint_as_float(cc.y & 0xFFFF0000u);
    float ge = __uint_as_float(cc.y << 16);
    float q[8];
    const unsigned yw[4] = {y0r.x, y0r.y, y0r.z, y0r.w};
    const unsigned gw[4] = {gg.x, gg.y, gg.z, gg.w};
#pragma unroll
    for (int p = 0; p < 4; ++p) {
        float ya = __uint_as_float(yw[p] << 16);
        float yb = __uint_as_float(yw[p] & 0xFFFF0000u);
        float ga = __uint_as_float(gw[p] << 16);
        float gb = __uint_as_float(gw[p] & 0xFFFF0000u);
        q[2 * p]     = cf * fmaxf(ya - ga, 0.0f);
        q[2 * p + 1] = cf * fmaxf(yb - gb, 0.0f);
    }
    unsigned r = 0;
    bool pending = val;
    while (__any(pending && rank >= r ? 1 : 0)) {
        if (pending && rank == r) {
            uint4 cur = myout[s0l];
            unsigned cw[4] = {cur.x, cur.y, cur.z, cur.w};
#pragma unroll
            for (int p = 0; p < 4; ++p) {
                __half2 hv = *reinterpret_cast<__half2*>(&cw[p]);
                float2 f = __half22float2(hv);
                f.x += q[2 * p];
                f.y += q[2 * p + 1];
                hv = __floats2half2_rn(f.x, f.y);
                cw[p] = *reinterpret_cast<unsigned*>(&hv);
            }
            myout[s0l] = make_uint4(cw[0], cw[1], cw[2], cw[3]);
            mydeg[s0l] += ge;
            pending = false;
        }
        ++r;
    }
}

// main accumulation: grid (K, MA), 128 threads (2 waves).
// R6 post-mortem: serial rank-ordered rounds (LDS RAW chains) were the real
// cost, not LDS issue. New scheme: rank-0 lanes (~92%) do ONE straight-line
// RMW (compiler can pipeline across halves/iters); rank>0 lanes append their
// 8B record to a per-wave LDS overflow queue, drained with process_dups at
// loop end (and mid-loop via guard — worst-case-safe).
__global__ __launch_bounds__(128)
void accum_kernel(const uint2* __restrict__ w0coef, const unsigned* __restrict__ bb,
                  const uint4* __restrict__ yT,
                  float* __restrict__ pdegp, __half2* __restrict__ pout,
                  int N, int Npad) {
    __shared__ uint4  outw[2][SBUCKET];           // 16 KB: [wave][node] = 4x half2
    __shared__ float  degw[2][SBUCKET];           // 4 KB:  [wave][node]
    __shared__ uint2  ovq[2][QCAP];               // 6 KB:  per-wave overflow queue
    __shared__ unsigned ovn[2];
    int k = blockIdx.x, m = blockIdx.y, tid = threadIdx.x;
    int n0 = k << S_LOG;
    unsigned lane = tid & 63;
    unsigned wv = tid >> 6;

    uint4 z4i = make_uint4(0u, 0u, 0u, 0u);
    for (int i = tid; i < 2 * SBUCKET; i += 128)
        ((uint4*)outw)[i] = z4i;
    for (int i = tid; i < 2 * SBUCKET; i += 128)
        ((float*)degw)[i] = 0.0f;
    if (tid < 2) ovn[tid] = 0u;
    unsigned lo = bb[k], hi = bb[k + 1];
    unsigned cnt = hi - lo;
    unsigned slice = (cnt + MA - 1) / MA;
    unsigned slo = lo + m * slice;
    unsigned shi = min(slo + slice, hi);
    __syncthreads();

    uint4* myout = outw[wv];
    float* mydeg = degw[wv];

    unsigned i0 = slo + tid;
    uint2 z2 = make_uint2(0u, 0u);
    uint2 c0 = z2, c1 = z2, d0 = z2, d1 = z2;
    uint4 zg = make_uint4(0u, 0u, 0u, 0u);
    uint4 g0 = zg, g1 = zg, yg0 = zg, yg1 = zg;
    bool vc0 = i0 < shi,       vc1 = i0 + 128 < shi;
    bool vd0 = i0 + 256 < shi, vd1 = i0 + 384 < shi;
    if (vc0) c0 = w0coef[i0];
    if (vc1) c1 = w0coef[i0 + 128];
    if (vd0) d0 = w0coef[i0 + 256];
    if (vd1) d1 = w0coef[i0 + 384];
    if (vc0) { g0 = yT[c0.x & 0x1FFFFu]; yg0 = yT[n0 + (c0.x >> 17)]; }
    if (vc1) { g1 = yT[c1.x & 0x1FFFFu]; yg1 = yT[n0 + (c1.x >> 17)]; }

    while (__any(vc0)) {
        // overflow-guard: worst case adds 126 entries this iteration
        if (ovn[wv] > (QCAP - 130)) {
            unsigned qn = ovn[wv];
            for (unsigned qb = 0; qb < qn; qb += 64) {
                unsigned qidx = qb + lane;
                uint2 qc = (qidx < qn) ? ovq[wv][qidx] : z2;
                process_dups(myout, mydeg, yT, n0, qc, qidx < qn, lane);
            }
            if (lane == 0) ovn[wv] = 0u;
        }

        uint4 h0 = zg, h1 = zg, yh0 = zg, yh1 = zg;
        if (vd0) { h0 = yT[d0.x & 0x1FFFFu]; yh0 = yT[n0 + (d0.x >> 17)]; }
        if (vd1) { h1 = yT[d1.x & 0x1FFFFu]; yh1 = yT[n0 + (d1.x >> 17)]; }
        uint2 e0 = z2, e1 = z2;
        bool ve0 = i0 + 512 < shi, ve1 = i0 + 640 < shi;
        if (ve0) e0 = w0coef[i0 + 512];
        if (ve1) e1 = w0coef[i0 + 640];

#pragma unroll
        for (int half = 0; half < 2; ++half) {
            bool val = half ? vc1 : vc0;
            uint2 cc = half ? c1 : c0;
            uint4 gg = half ? g1 : g0;
            uint4 y0r = half ? yg1 : yg0;
            unsigned s0l = cc.x >> 17;
            // group lanes by (s0l, val) via ballots
            unsigned long long mm = ~0ull;
#pragma unroll
            for (int b = 0; b < 9; ++b) {
                unsigned long long vb = __ballot((s0l >> b) & 1u);
                mm &= ((s0l >> b) & 1u) ? vb : ~vb;
            }
            {
                unsigned long long vb = __ballot(val ? 1 : 0);
                mm &= val ? vb : ~vb;
            }
            unsigned rank = __popcll(mm & ((1ull << lane) - 1ull));
            if (val) {
                if (rank == 0) {
                    // sole visitor: single straight-line RMW (pipelineable)
                    float cf = __uint_as_float(cc.y & 0xFFFF0000u);
                    float ge = __uint_as_float(cc.y << 16);
                    const unsigned yw[4] = {y0r.x, y0r.y, y0r.z, y0r.w};
                    const unsigned gw[4] = {gg.x, gg.y, gg.z, gg.w};
                    float q[8];
#pragma unroll
                    for (int p = 0; p < 4; ++p) {
                        float ya = __uint_as_float(yw[p] << 16);
                        float yb = __uint_as_float(yw[p] & 0xFFFF0000u);
                        float ga = __uint_as_float(gw[p] << 16);
                        float gb = __uint_as_float(gw[p] & 0xFFFF0000u);
                        q[2 * p]     = cf * fmaxf(ya - ga, 0.0f);
                        q[2 * p + 1] = cf * fmaxf(yb - gb, 0.0f);
                    }
                    uint4 cur = myout[s0l];
                    unsigned cw[4] = {cur.x, cur.y, cur.z, cur.w};
#pragma unroll
                    for (int p = 0; p < 4; ++p) {
                        __half2 hv = *reinterpret_cast<__half2*>(&cw[p]);
                        float2 f = __half22float2(hv);
                        f.x += q[2 * p];
                        f.y += q[2 * p + 1];
                        hv = __floats2half2_rn(f.x, f.y);
                        cw[p] = *reinterpret_cast<unsigned*>(&hv);
                    }
                    myout[s0l] = make_uint4(cw[0], cw[1], cw[2], cw[3]);
                    mydeg[s0l] += ge;
                } else {
                    // duplicate: defer to per-wave overflow queue
                    unsigned qi = atomicAdd(&ovn[wv], 1u);
                    ovq[wv][qi] = cc;
                }
            }
        }

        c0 = d0; c1 = d1; d0 = e0; d1 = e1;
        g0 = h0; g1 = h1; yg0 = yh0; yg1 = yh1;
        vc0 = vd0; vc1 = vd1; vd0 = ve0; vd1 = ve1;
        i0 += 256;
    }

    // final drain of the overflow queue (per wave)
    {
        unsigned qn = ovn[wv];
        for (unsigned qb = 0; qb < qn; qb += 64) {
            unsigned qidx = qb + lane;
            uint2 qc = (qidx < qn) ? ovq[wv][qidx] : z2;
            process_dups(myout, mydeg, yT, n0, qc, qidx < qn, lane);
        }
    }
    __syncthreads();

    for (int i = tid; i < SBUCKET; i += 128)
        pdegp[(size_t)m * Npad + n0 + i] = degw[0][i] + degw[1][i];
    for (int j = tid; j < SBUCKET; j += 128) {
        uint4 a = outw[0][j];
        uint4 b = outw[1][j];
        unsigned aw[4] = {a.x, a.y, a.z, a.w};
        unsigned bw[4] = {b.x, b.y, b.z, b.w};
#pragma unroll
        for (int p = 0; p < 4; ++p) {
            float2 fa = __half22float2(*reinterpret_cast<__half2*>(&aw[p]));
            float2 fb = __half22float2(*reinterpret_cast<__half2*>(&bw[p]));
            pout[((size_t)m * 4 + p) * Npad + n0 + j] =
                __floats2half2_rn(fa.x + fb.x, fa.y + fb.y);
        }
    }
}

// out[b*N+n] = 1 - (sum_m pout)/deg^2. One thread per node.
__global__ __launch_bounds__(256)
void finalize_kernel(const float* __restrict__ pdegp, const __half2* __restrict__ pout,
                     float* __restrict__ out, int N, int Npad) {
    int n = blockIdx.x * blockDim.x + threadIdx.x;
    if (n >= N) return;
    float d = 0.0f;
#pragma unroll
    for (int m = 0; m < MA; ++m) d += pdegp[(size_t)m * Npad + n];
    float inv = 1.0f / (d * d);
#pragma unroll
    for (int p = 0; p < 4; ++p) {
        float sx = 0.0f, sy = 0.0f;
#pragma unroll
        for (int m = 0; m < MA; ++m) {
            float2 f = __half22float2(pout[((size_t)m * 4 + p) * Npad + n]);
            sx += f.x; sy += f.y;
        }
        out[(size_t)(2 * p) * N + n]     = 1.0f - sx * inv;
        out[(size_t)(2 * p + 1) * N + n] = 1.0f - sy * inv;
    }
}

// ---------------- fallback (R1 path) ----------------

__global__ void fill_one_kernel(float* __restrict__ out, int n) {
    int i = blockIdx.x * blockDim.x + threadIdx.x;
    if (i < n) out[i] = 1.0f;
}

__global__ void zero_kernel(float* __restrict__ p, int n) {
    int i = blockIdx.x * blockDim.x + threadIdx.x;
    if (i < n) p[i] = 0.0f;
}

__global__ void deg_kernel(const float* __restrict__ gea,
                           const int* __restrict__ ei0,
                           float* __restrict__ deg, int E) {
    int e = blockIdx.x * blockDim.x + threadIdx.x;
    if (e < E) atomicAdd(&deg[ei0[e]], gea[e]);
}

__global__ void edge_kernel(const float* __restrict__ y,
                            const float* __restrict__ dw,
                            const int* __restrict__ ei0,
                            const int* __restrict__ ei1,
                            const float* __restrict__ deg,
                            float* __restrict__ out,
                            int E, int N) {
    int e = blockIdx.x * blockDim.x + threadIdx.x;
    if (e >= E) return;
    int s0 = ei0[e];
    int s1 = ei1[e];
    float d = deg[s0];
    float inv = 1.0f / (d * d);
    float sig = 1.0f / (1.0f + __expf(-dw[e]));
    float coef = sqrtf(sig) * inv;
#pragma unroll
    for (int b = 0; b < BATCH; ++b) {
        float y0 = y[(size_t)b * N + s0];
        float y1 = y[(size_t)b * N + s1];
        float gm = coef * fmaxf(y0 - y1, 0.0f);
        if (gm != 0.0f) atomicAdd(&out[(size_t)b * N + s0], -gm);
    }
}

// ---------------- launch ----------------

extern "C" void kernel_launch(void* const* d_in, const int* in_sizes, int n_in,
                              void* d_out, int out_size, void* d_ws, size_t ws_size,
                              hipStream_t stream) {
    const float* y   = (const float*)d_in[0];   // [B,N]
    const float* gea = (const float*)d_in[2];   // [E]
    const float* dw  = (const float*)d_in[3];   // [E]
    const int*   ei  = (const int*)d_in[4];     // [2,E]

    const int E = in_sizes[2];
    const int N = in_sizes[0] / BATCH;
    const int* ei0 = ei;
    const int* ei1 = ei + E;

    const int K = (N + SBUCKET - 1) >> S_LOG;
    const int Npad = K << S_LOG;

    size_t o_yT     = 0;
    size_t o_rcf    = o_yT     + alignup((size_t)Npad * 16);
    size_t o_counts = o_rcf    + alignup((size_t)E * 8);
    size_t o_base   = o_counts + alignup((size_t)KC * CB * 4);
    size_t o_tot    = o_base   + alignup((size_t)KC * CB * 4);
    size_t o_bb     = o_tot    + alignup((size_t)KC * 4);
    size_t o_pdegp  = o_bb     + alignup((size_t)(KC + 1) * 4);
    size_t o_pout   = o_pdegp  + alignup((size_t)MA * Npad * 4);
    size_t need     = o_pout   + alignup((size_t)MA * 4 * Npad * 4);

    if (K <= KC && N <= 131071 && ws_size >= need) {
        char* w = (char*)d_ws;
        uint4*    yT     = (uint4*)(w + o_yT);
        uint2*    w0coef = (uint2*)(w + o_rcf);
        unsigned* counts = (unsigned*)(w + o_counts);
        unsigned* base   = (unsigned*)(w + o_base);
        unsigned* tot    = (unsigned*)(w + o_tot);
        unsigned* bb     = (unsigned*)(w + o_bb);
        float*    pdegp  = (float*)(w + o_pdegp);
        __half2*  pout   = (__half2*)(w + o_pout);

        int tb = (Npad + 255) / 256;
        count_transpose_kernel<<<CB + tb, 256, 0, stream>>>(ei0, counts, y, yT,
                                                            E, N, Npad);
        scanB1_kernel<<<K, 256, 0, stream>>>(counts, base, tot);
        scanC_kernel<<<1, KC, 0, stream>>>(tot, bb, E, K);
        scatter_kernel<<<CB, 256, 0, stream>>>(ei0, ei1, dw, gea, base, bb,
                                               w0coef, E);
        accum_kernel<<<dim3(K, MA), 128, 0, stream>>>(w0coef, bb, yT,
                                                      pdegp, pout, N, Npad);
        finalize_kernel<<<(N + 255) / 256, 256, 0, stream>>>(
            pdegp, pout, (float*)d_out, N, Npad);
    } else {
        float* deg = (float*)d_ws;
        zero_kernel<<<(N + 255) / 256, 256, 0, stream>>>(deg, N);
        fill_one_kernel<<<(out_size + 255) / 256, 256, 0, stream>>>((float*)d_out, out_size);
        deg_kernel<<<(E + 255) / 256, 256, 0, stream>>>(gea, ei0, deg, E);
        edge_kernel<<<(E + 255) / 256, 256, 0, stream>>>(y, dw, ei0, ei1, deg,
                                                         (float*)d_out, E, N);
    }
}

// Round 8
// 154.225 us; speedup vs baseline: 1.0704x; 1.0200x over previous
//
#include <hip/hip_runtime.h>
#include <hip/hip_fp16.h>

#define BATCH 8
#define S_LOG 9
#define SBUCKET 512          // nodes per bucket
#define KC 256               // max buckets (N <= 131071)
#define CB 1024              // blocks for count/scatter
#define TTILE 2048           // edges per sort tile
#define EPT 8                // edges per thread per tile (contiguous)
#define SCAP 15360           // records per accum sort chunk (120 KB LDS)

static inline size_t alignup(size_t x) { return (x + 255) & ~(size_t)255; }

__device__ __forceinline__ unsigned bf16hi(unsigned u) {
    // fp32 -> bf16 (rne), returned in LOW 16 bits
    return (u + 0x7FFFu + ((u >> 16) & 1u)) >> 16;
}

__device__ __forceinline__ int aligned_chunk(int E) {
    return (((E + CB - 1) / CB) + 15) & ~15;    // 16-elem aligned => 64B
}

// ---------------- pipeline kernels ----------------

// fused: blocks [0,CB) bucket-count (int4 loads, uint LDS atomics); blocks [CB,...)
// transpose y -> yT[node] = 8 bf16 (uint4)
__global__ __launch_bounds__(256)
void count_transpose_kernel(const int* __restrict__ ei0, unsigned* __restrict__ counts,
                            const float* __restrict__ y, uint4* __restrict__ yT,
                            int E, int N, int Npad) {
    __shared__ unsigned cnt[KC];
    int tid = threadIdx.x;
    if (blockIdx.x >= CB) {
        int n = (blockIdx.x - CB) * 256 + tid;
        if (n < Npad) {
            uint4 o = make_uint4(0u, 0u, 0u, 0u);
            if (n < N) {
                unsigned p[8];
#pragma unroll
                for (int b = 0; b < BATCH; ++b)
                    p[b] = bf16hi(__float_as_uint(y[(size_t)b * N + n]));
                o = make_uint4(p[0] | (p[1] << 16), p[2] | (p[3] << 16),
                               p[4] | (p[5] << 16), p[6] | (p[7] << 16));
            }
            yT[n] = o;
        }
        return;
    }
    cnt[tid] = 0;
    __syncthreads();
    int chunk = aligned_chunk(E);
    int lo = blockIdx.x * chunk;
    int hi = min(lo + chunk, E);
    for (int bi = lo; bi < hi; bi += 1024) {
        int idx = bi + tid * 4;
        if (idx + 4 <= hi) {
            int4 v = *(const int4*)(ei0 + idx);
            atomicAdd(&cnt[(unsigned)v.x >> S_LOG], 1u);
            atomicAdd(&cnt[(unsigned)v.y >> S_LOG], 1u);
            atomicAdd(&cnt[(unsigned)v.z >> S_LOG], 1u);
            atomicAdd(&cnt[(unsigned)v.w >> S_LOG], 1u);
        } else {
#pragma unroll
            for (int j = 0; j < 4; ++j) {
                int i2 = idx + j;
                if (i2 < hi) atomicAdd(&cnt[(unsigned)ei0[i2] >> S_LOG], 1u);
            }
        }
    }
    __syncthreads();
    counts[(size_t)tid * CB + blockIdx.x] = cnt[tid];   // [bucket][block]
}

// scanB1: one block per bucket — local exclusive prefix of counts[k][0..CB) -> base,
// and bucket total -> tot[k].
__global__ __launch_bounds__(256)
void scanB1_kernel(const unsigned* __restrict__ counts, unsigned* __restrict__ base,
                   unsigned* __restrict__ tot) {
    __shared__ unsigned ssum[256];
    int k = blockIdx.x, tid = threadIdx.x;
    const uint4* row4 = (const uint4*)(counts + (size_t)k * CB);
    uint4 v = row4[tid];
    unsigned lsum = v.x + v.y + v.z + v.w;
    ssum[tid] = lsum;
    __syncthreads();
    for (int off = 1; off < 256; off <<= 1) {
        unsigned u = ssum[tid];
        unsigned a = (tid >= off) ? ssum[tid - off] : 0u;
        __syncthreads();
        ssum[tid] = u + a;
        __syncthreads();
    }
    unsigned ex = ssum[tid] - lsum;
    if (tid == 255) tot[k] = ssum[255];
    uint4 o;
    o.x = ex;
    o.y = ex + v.x;
    o.z = o.y + v.y;
    o.w = o.z + v.z;
    ((uint4*)(base + (size_t)k * CB))[tid] = o;
}

// scanC: one block — exclusive scan of bucket totals -> bb[0..KC], bb[KC]=E
__global__ void scanC_kernel(const unsigned* __restrict__ tot,
                             unsigned* __restrict__ bb, int E, int K) {
    __shared__ unsigned sb[KC];
    int t = threadIdx.x;
    unsigned v = (t < K) ? tot[t] : 0u;
    sb[t] = v;
    __syncthreads();
    for (int off = 1; off < KC; off <<= 1) {
        unsigned u = sb[t];
        unsigned a = (t >= off) ? sb[t - off] : 0u;
        __syncthreads();
        sb[t] = u + a;
        __syncthreads();
    }
    bb[t] = sb[t] - v;
    if (t == KC - 1) bb[KC] = (unsigned)E;
}

// scatter: bucket-sort edges into w0coef records (uint LDS atomics — cheap).
// Per-thread CONTIGUOUS EPT elements => int4/float4 vector loads.
// record: .x = s1 | s0l<<17 ; .y = bf16(coef)<<16 | bf16(gea)
__global__ __launch_bounds__(256)
void scatter_kernel(const int* __restrict__ ei0, const int* __restrict__ ei1,
                    const float* __restrict__ dw, const float* __restrict__ gea,
                    const unsigned* __restrict__ base, const unsigned* __restrict__ bb,
                    uint2* __restrict__ w0coef, int E) {
    __shared__ unsigned cursor[KC];
    __shared__ unsigned h[KC];
    __shared__ unsigned tstart[KC];
    __shared__ unsigned wsum[4];
    __shared__ uint2 srec[TTILE];            // 16 KB
    __shared__ unsigned char skey[TTILE];    // 2 KB
    int tid = threadIdx.x;
    cursor[tid] = base[(size_t)tid * CB + blockIdx.x] + bb[tid];
    int chunk = aligned_chunk(E);
    int lo = blockIdx.x * chunk;
    int hi = min(lo + chunk, E);
    __syncthreads();

    for (int tileLo = lo; tileLo < hi; tileLo += TTILE) {
        int tn = min(TTILE, hi - tileLo);
        h[tid] = 0;
        __syncthreads();

        int base_off = tid * EPT;
        unsigned k_r[EPT], w0_r[EPT], pk_r[EPT], rk_r[EPT];
        int s0a[EPT], s1a[EPT];
        float dwa[EPT], gea_a[EPT];
        bool anyv = base_off < tn;
        if (base_off + EPT <= tn) {
            // vector loads (tileLo 16-aligned, base_off multiple of 8)
            const int4* p0 = (const int4*)(ei0 + tileLo + base_off);
            const int4* p1 = (const int4*)(ei1 + tileLo + base_off);
            const float4* pd = (const float4*)(dw + tileLo + base_off);
            const float4* pg = (const float4*)(gea + tileLo + base_off);
            int4 a0 = p0[0], a1 = p0[1];
            int4 b0 = p1[0], b1 = p1[1];
            float4 d0 = pd[0], d1 = pd[1];
            float4 g0 = pg[0], g1 = pg[1];
            s0a[0]=a0.x; s0a[1]=a0.y; s0a[2]=a0.z; s0a[3]=a0.w;
            s0a[4]=a1.x; s0a[5]=a1.y; s0a[6]=a1.z; s0a[7]=a1.w;
            s1a[0]=b0.x; s1a[1]=b0.y; s1a[2]=b0.z; s1a[3]=b0.w;
            s1a[4]=b1.x; s1a[5]=b1.y; s1a[6]=b1.z; s1a[7]=b1.w;
            dwa[0]=d0.x; dwa[1]=d0.y; dwa[2]=d0.z; dwa[3]=d0.w;
            dwa[4]=d1.x; dwa[5]=d1.y; dwa[6]=d1.z; dwa[7]=d1.w;
            gea_a[0]=g0.x; gea_a[1]=g0.y; gea_a[2]=g0.z; gea_a[3]=g0.w;
            gea_a[4]=g1.x; gea_a[5]=g1.y; gea_a[6]=g1.z; gea_a[7]=g1.w;
#pragma unroll
            for (int j = 0; j < EPT; ++j) k_r[j] = 0u;   // mark all valid below
#pragma unroll
            for (int j = 0; j < EPT; ++j) {
                unsigned k = (unsigned)s0a[j] >> S_LOG;
                unsigned s0l = (unsigned)(s0a[j] & (SBUCKET - 1));
                k_r[j] = k;
                w0_r[j] = (unsigned)s1a[j] | (s0l << 17);
                float sig = 1.0f / (1.0f + __expf(-dwa[j]));
                pk_r[j] = (bf16hi(__float_as_uint(sqrtf(sig))) << 16) |
                          bf16hi(__float_as_uint(gea_a[j]));
            }
#pragma unroll
            for (int j = 0; j < EPT; ++j)
                rk_r[j] = atomicAdd(&h[k_r[j]], 1u);
        } else {
#pragma unroll
            for (int j = 0; j < EPT; ++j) {
                int off = base_off + j;
                k_r[j] = 0xFFFFFFFFu;
                if (off < tn) {
                    int i = tileLo + off;
                    int s0v = ei0[i];
                    int s1v = ei1[i];
                    unsigned k = (unsigned)s0v >> S_LOG;
                    unsigned s0l = (unsigned)(s0v & (SBUCKET - 1));
                    k_r[j] = k;
                    w0_r[j] = (unsigned)s1v | (s0l << 17);
                    float sig = 1.0f / (1.0f + __expf(-dw[i]));
                    pk_r[j] = (bf16hi(__float_as_uint(sqrtf(sig))) << 16) |
                              bf16hi(__float_as_uint(gea[i]));
                }
            }
#pragma unroll
            for (int j = 0; j < EPT; ++j)
                if (k_r[j] != 0xFFFFFFFFu) rk_r[j] = atomicAdd(&h[k_r[j]], 1u);
        }
        bool fullv = base_off + EPT <= tn;
        __syncthreads();

        // exclusive scan of h[256] via wave shuffles
        unsigned hv = h[tid];
        unsigned v = hv;
        unsigned lane = tid & 63;
        unsigned wv = tid >> 6;
#pragma unroll
        for (int off = 1; off < 64; off <<= 1) {
            unsigned t = __shfl_up(v, off, 64);
            if (lane >= off) v += t;
        }
        if (lane == 63) wsum[wv] = v;
        __syncthreads();
        unsigned addv = 0;
#pragma unroll
        for (unsigned w = 0; w < 4; ++w)
            if (w < wv) addv += wsum[w];
        tstart[tid] = v + addv - hv;
        __syncthreads();

        if (fullv) {
#pragma unroll
            for (int j = 0; j < EPT; ++j) {
                unsigned slot = tstart[k_r[j]] + rk_r[j];
                srec[slot] = make_uint2(w0_r[j], pk_r[j]);
                skey[slot] = (unsigned char)k_r[j];
            }
        } else if (anyv) {
#pragma unroll
            for (int j = 0; j < EPT; ++j)
                if (k_r[j] != 0xFFFFFFFFu) {
                    unsigned slot = tstart[k_r[j]] + rk_r[j];
                    srec[slot] = make_uint2(w0_r[j], pk_r[j]);
                    skey[slot] = (unsigned char)k_r[j];
                }
        }
        __syncthreads();

        for (int i = tid; i < tn; i += 256) {
            uint2 u = srec[i];
            unsigned k = skey[i];
            unsigned pos = cursor[k] + ((unsigned)i - tstart[k]);
            w0coef[pos] = u;
        }
        __syncthreads();
        cursor[tid] += h[tid];
        __syncthreads();
    }
}

// accum (owner-computes): one block per bucket, 512 threads, 1 node/thread.
// Per chunk (<=SCAP records): counting-sort the bucket's records by node into
// LDS (pass1 count + 8-wave scan + pass2 scatter), then each thread walks its
// node's contiguous run accumulating in fp32 REGISTERS (no ballots, no shared
// RMW, no duplicate hazards). Writes final out = 1 - acc/deg^2 directly.
__global__ __launch_bounds__(512)
void accum_kernel(const uint2* __restrict__ w0coef, const unsigned* __restrict__ bb,
                  const uint4* __restrict__ yT,
                  float* __restrict__ out, int N) {
    __shared__ uint2 srt[SCAP];              // 120 KB sorted records
    __shared__ unsigned bcnt[SBUCKET];       // 2 KB per-node count (chunk)
    __shared__ unsigned boff[SBUCKET];       // 2 KB exclusive scan
    __shared__ unsigned bcur[SBUCKET];       // 2 KB scatter cursors
    __shared__ unsigned wsums[8];
    int k = blockIdx.x, tid = threadIdx.x;
    int n0 = k << S_LOG;
    unsigned lane = tid & 63;
    unsigned wvi = tid >> 6;

    unsigned lo = bb[k], hi = bb[k + 1];

    // my node's y0, unpacked once
    uint4 y0r = yT[n0 + tid];
    float y0f[8];
    {
        unsigned yw[4] = {y0r.x, y0r.y, y0r.z, y0r.w};
#pragma unroll
        for (int p = 0; p < 4; ++p) {
            y0f[2 * p]     = __uint_as_float(yw[p] << 16);
            y0f[2 * p + 1] = __uint_as_float(yw[p] & 0xFFFF0000u);
        }
    }
    float acc[8] = {0.f, 0.f, 0.f, 0.f, 0.f, 0.f, 0.f, 0.f};
    float dega = 0.f;

    for (unsigned cbase = lo; cbase < hi; cbase += SCAP) {
        unsigned cn = min((unsigned)SCAP, hi - cbase);
        bcnt[tid] = 0u;
        __syncthreads();
        // pass1: count s0l (coalesced read, cheap uint LDS atomics)
        for (unsigned i = tid; i < cn; i += 512)
            atomicAdd(&bcnt[w0coef[cbase + i].x >> 17], 1u);
        __syncthreads();
        // exclusive scan of bcnt[512] across 8 waves
        unsigned myc = bcnt[tid];
        unsigned v = myc;
#pragma unroll
        for (int off = 1; off < 64; off <<= 1) {
            unsigned t = __shfl_up(v, off, 64);
            if (lane >= off) v += t;
        }
        if (lane == 63) wsums[wvi] = v;
        __syncthreads();
        unsigned add = 0;
#pragma unroll
        for (unsigned w = 0; w < 8; ++w)
            if (w < wvi) add += wsums[w];
        unsigned myoff = v + add - myc;
        boff[tid] = myoff;
        bcur[tid] = myoff;
        __syncthreads();
        // pass2: scatter records into srt sorted by node (L2-hot re-read)
        for (unsigned i = tid; i < cn; i += 512) {
            uint2 r = w0coef[cbase + i];
            unsigned slot = atomicAdd(&bcur[r.x >> 17], 1u);
            srt[slot] = r;
        }
        __syncthreads();
        // owner phase: walk my run with a 2-deep prefetch pipeline
        unsigned s = myoff, e = myoff + myc;
        uint2 r0 = make_uint2(0u, 0u), r1 = make_uint2(0u, 0u);
        uint4 g0 = make_uint4(0u, 0u, 0u, 0u), g1 = g0;
        if (s < e)     { r0 = srt[s];     g0 = yT[r0.x & 0x1FFFFu]; }
        if (s + 1 < e) { r1 = srt[s + 1]; g1 = yT[r1.x & 0x1FFFFu]; }
        for (unsigned i = s; i < e; ++i) {
            uint2 rc = r0; uint4 gc = g0;
            r0 = r1; g0 = g1;
            if (i + 2 < e) { r1 = srt[i + 2]; g1 = yT[r1.x & 0x1FFFFu]; }
            float cf = __uint_as_float(rc.y & 0xFFFF0000u);
            float ge = __uint_as_float(rc.y << 16);
            unsigned gw[4] = {gc.x, gc.y, gc.z, gc.w};
#pragma unroll
            for (int p = 0; p < 4; ++p) {
                float ga = __uint_as_float(gw[p] << 16);
                float gb = __uint_as_float(gw[p] & 0xFFFF0000u);
                acc[2 * p]     += cf * fmaxf(y0f[2 * p]     - ga, 0.0f);
                acc[2 * p + 1] += cf * fmaxf(y0f[2 * p + 1] - gb, 0.0f);
            }
            dega += ge;
        }
        __syncthreads();   // all owners done before LDS reuse next chunk
    }

    // final write: out[b*N + n] = 1 - acc[b]/deg^2 (coalesced per batch)
    int n = n0 + tid;
    if (n < N) {
        float invd = (dega != 0.0f) ? 1.0f / (dega * dega) : 0.0f;
#pragma unroll
        for (int b = 0; b < BATCH; ++b)
            out[(size_t)b * N + n] = 1.0f - acc[b] * invd;
    }
}

// ---------------- fallback (R1 path) ----------------

__global__ void fill_one_kernel(float* __restrict__ out, int n) {
    int i = blockIdx.x * blockDim.x + threadIdx.x;
    if (i < n) out[i] = 1.0f;
}

__global__ void zero_kernel(float* __restrict__ p, int n) {
    int i = blockIdx.x * blockDim.x + threadIdx.x;
    if (i < n) p[i] = 0.0f;
}

__global__ void deg_kernel(const float* __restrict__ gea,
                           const int* __restrict__ ei0,
                           float* __restrict__ deg, int E) {
    int e = blockIdx.x * blockDim.x + threadIdx.x;
    if (e < E) atomicAdd(&deg[ei0[e]], gea[e]);
}

__global__ void edge_kernel(const float* __restrict__ y,
                            const float* __restrict__ dw,
                            const int* __restrict__ ei0,
                            const int* __restrict__ ei1,
                            const float* __restrict__ deg,
                            float* __restrict__ out,
                            int E, int N) {
    int e = blockIdx.x * blockDim.x + threadIdx.x;
    if (e >= E) return;
    int s0 = ei0[e];
    int s1 = ei1[e];
    float d = deg[s0];
    float inv = 1.0f / (d * d);
    float sig = 1.0f / (1.0f + __expf(-dw[e]));
    float coef = sqrtf(sig) * inv;
#pragma unroll
    for (int b = 0; b < BATCH; ++b) {
        float y0 = y[(size_t)b * N + s0];
        float y1 = y[(size_t)b * N + s1];
        float gm = coef * fmaxf(y0 - y1, 0.0f);
        if (gm != 0.0f) atomicAdd(&out[(size_t)b * N + s0], -gm);
    }
}

// ---------------- launch ----------------

extern "C" void kernel_launch(void* const* d_in, const int* in_sizes, int n_in,
                              void* d_out, int out_size, void* d_ws, size_t ws_size,
                              hipStream_t stream) {
    const float* y   = (const float*)d_in[0];   // [B,N]
    const float* gea = (const float*)d_in[2];   // [E]
    const float* dw  = (const float*)d_in[3];   // [E]
    const int*   ei  = (const int*)d_in[4];     // [2,E]

    const int E = in_sizes[2];
    const int N = in_sizes[0] / BATCH;
    const int* ei0 = ei;
    const int* ei1 = ei + E;

    const int K = (N + SBUCKET - 1) >> S_LOG;
    const int Npad = K << S_LOG;

    size_t o_yT     = 0;
    size_t o_rcf    = o_yT     + alignup((size_t)Npad * 16);
    size_t o_counts = o_rcf    + alignup((size_t)E * 8);
    size_t o_base   = o_counts + alignup((size_t)KC * CB * 4);
    size_t o_tot    = o_base   + alignup((size_t)KC * CB * 4);
    size_t o_bb     = o_tot    + alignup((size_t)KC * 4);
    size_t need     = o_bb     + alignup((size_t)(KC + 1) * 4);

    if (K <= KC && N <= 131071 && ws_size >= need) {
        char* w = (char*)d_ws;
        uint4*    yT     = (uint4*)(w + o_yT);
        uint2*    w0coef = (uint2*)(w + o_rcf);
        unsigned* counts = (unsigned*)(w + o_counts);
        unsigned* base   = (unsigned*)(w + o_base);
        unsigned* tot    = (unsigned*)(w + o_tot);
        unsigned* bb     = (unsigned*)(w + o_bb);

        int tb = (Npad + 255) / 256;
        count_transpose_kernel<<<CB + tb, 256, 0, stream>>>(ei0, counts, y, yT,
                                                            E, N, Npad);
        scanB1_kernel<<<K, 256, 0, stream>>>(counts, base, tot);
        scanC_kernel<<<1, KC, 0, stream>>>(tot, bb, E, K);
        scatter_kernel<<<CB, 256, 0, stream>>>(ei0, ei1, dw, gea, base, bb,
                                               w0coef, E);
        accum_kernel<<<K, 512, 0, stream>>>(w0coef, bb, yT, (float*)d_out, N);
    } else {
        float* deg = (float*)d_ws;
        zero_kernel<<<(N + 255) / 256, 256, 0, stream>>>(deg, N);
        fill_one_kernel<<<(out_size + 255) / 256, 256, 0, stream>>>((float*)d_out, out_size);
        deg_kernel<<<(E + 255) / 256, 256, 0, stream>>>(gea, ei0, deg, E);
        edge_kernel<<<(E + 255) / 256, 256, 0, stream>>>(y, dw, ei0, ei1, deg,
                                                         (float*)d_out, E, N);
    }
}

// Round 9
// 149.745 us; speedup vs baseline: 1.1024x; 1.0299x over previous
//
#include <hip/hip_runtime.h>
#include <hip/hip_fp16.h>

#define BATCH 8
#define S_LOG 9
#define SBUCKET 512          // nodes per bucket
#define KC 256               // max buckets (N <= 131071)
#define CB 1024              // blocks for count/scatter
#define TTILE 2048           // edges per sort tile
#define EPT 8                // edges per thread per tile (contiguous)
#define RPT 30               // accum records per thread per chunk (registers)
#define SCAP (RPT * 512)     // 15360 records per accum sort chunk (120 KB LDS)

static inline size_t alignup(size_t x) { return (x + 255) & ~(size_t)255; }

__device__ __forceinline__ unsigned bf16hi(unsigned u) {
    // fp32 -> bf16 (rne), returned in LOW 16 bits
    return (u + 0x7FFFu + ((u >> 16) & 1u)) >> 16;
}

__device__ __forceinline__ int aligned_chunk(int E) {
    return (((E + CB - 1) / CB) + 15) & ~15;    // 16-elem aligned => 64B
}

// ---------------- pipeline kernels ----------------

// fused: blocks [0,CB) bucket-count (int4 loads, uint LDS atomics); blocks [CB,...)
// transpose y -> yT[node] = 8 bf16 (uint4)
__global__ __launch_bounds__(256)
void count_transpose_kernel(const int* __restrict__ ei0, unsigned* __restrict__ counts,
                            const float* __restrict__ y, uint4* __restrict__ yT,
                            int E, int N, int Npad) {
    __shared__ unsigned cnt[KC];
    int tid = threadIdx.x;
    if (blockIdx.x >= CB) {
        int n = (blockIdx.x - CB) * 256 + tid;
        if (n < Npad) {
            uint4 o = make_uint4(0u, 0u, 0u, 0u);
            if (n < N) {
                unsigned p[8];
#pragma unroll
                for (int b = 0; b < BATCH; ++b)
                    p[b] = bf16hi(__float_as_uint(y[(size_t)b * N + n]));
                o = make_uint4(p[0] | (p[1] << 16), p[2] | (p[3] << 16),
                               p[4] | (p[5] << 16), p[6] | (p[7] << 16));
            }
            yT[n] = o;
        }
        return;
    }
    cnt[tid] = 0;
    __syncthreads();
    int chunk = aligned_chunk(E);
    int lo = blockIdx.x * chunk;
    int hi = min(lo + chunk, E);
    for (int bi = lo; bi < hi; bi += 1024) {
        int idx = bi + tid * 4;
        if (idx + 4 <= hi) {
            int4 v = *(const int4*)(ei0 + idx);
            atomicAdd(&cnt[(unsigned)v.x >> S_LOG], 1u);
            atomicAdd(&cnt[(unsigned)v.y >> S_LOG], 1u);
            atomicAdd(&cnt[(unsigned)v.z >> S_LOG], 1u);
            atomicAdd(&cnt[(unsigned)v.w >> S_LOG], 1u);
        } else {
#pragma unroll
            for (int j = 0; j < 4; ++j) {
                int i2 = idx + j;
                if (i2 < hi) atomicAdd(&cnt[(unsigned)ei0[i2] >> S_LOG], 1u);
            }
        }
    }
    __syncthreads();
    counts[(size_t)tid * CB + blockIdx.x] = cnt[tid];   // [bucket][block]
}

// scanB1: one block per bucket — local exclusive prefix of counts[k][0..CB) -> base,
// and bucket total -> tot[k].
__global__ __launch_bounds__(256)
void scanB1_kernel(const unsigned* __restrict__ counts, unsigned* __restrict__ base,
                   unsigned* __restrict__ tot) {
    __shared__ unsigned ssum[256];
    int k = blockIdx.x, tid = threadIdx.x;
    const uint4* row4 = (const uint4*)(counts + (size_t)k * CB);
    uint4 v = row4[tid];
    unsigned lsum = v.x + v.y + v.z + v.w;
    ssum[tid] = lsum;
    __syncthreads();
    for (int off = 1; off < 256; off <<= 1) {
        unsigned u = ssum[tid];
        unsigned a = (tid >= off) ? ssum[tid - off] : 0u;
        __syncthreads();
        ssum[tid] = u + a;
        __syncthreads();
    }
    unsigned ex = ssum[tid] - lsum;
    if (tid == 255) tot[k] = ssum[255];
    uint4 o;
    o.x = ex;
    o.y = ex + v.x;
    o.z = o.y + v.y;
    o.w = o.z + v.z;
    ((uint4*)(base + (size_t)k * CB))[tid] = o;
}

// scanC: one block — exclusive scan of bucket totals -> bb[0..KC], bb[KC]=E
__global__ void scanC_kernel(const unsigned* __restrict__ tot,
                             unsigned* __restrict__ bb, int E, int K) {
    __shared__ unsigned sb[KC];
    int t = threadIdx.x;
    unsigned v = (t < K) ? tot[t] : 0u;
    sb[t] = v;
    __syncthreads();
    for (int off = 1; off < KC; off <<= 1) {
        unsigned u = sb[t];
        unsigned a = (t >= off) ? sb[t - off] : 0u;
        __syncthreads();
        sb[t] = u + a;
        __syncthreads();
    }
    bb[t] = sb[t] - v;
    if (t == KC - 1) bb[KC] = (unsigned)E;
}

// scatter: bucket-sort edges into w0coef records (uint LDS atomics — cheap).
// Per-thread CONTIGUOUS EPT elements => int4/float4 vector loads.
// record: .x = s1 | s0l<<17 ; .y = bf16(coef)<<16 | bf16(gea)
__global__ __launch_bounds__(256)
void scatter_kernel(const int* __restrict__ ei0, const int* __restrict__ ei1,
                    const float* __restrict__ dw, const float* __restrict__ gea,
                    const unsigned* __restrict__ base, const unsigned* __restrict__ bb,
                    uint2* __restrict__ w0coef, int E) {
    __shared__ unsigned cursor[KC];
    __shared__ unsigned h[KC];
    __shared__ unsigned tstart[KC];
    __shared__ unsigned wsum[4];
    __shared__ uint2 srec[TTILE];            // 16 KB
    __shared__ unsigned char skey[TTILE];    // 2 KB
    int tid = threadIdx.x;
    cursor[tid] = base[(size_t)tid * CB + blockIdx.x] + bb[tid];
    int chunk = aligned_chunk(E);
    int lo = blockIdx.x * chunk;
    int hi = min(lo + chunk, E);
    __syncthreads();

    for (int tileLo = lo; tileLo < hi; tileLo += TTILE) {
        int tn = min(TTILE, hi - tileLo);
        h[tid] = 0;
        __syncthreads();

        int base_off = tid * EPT;
        unsigned k_r[EPT], w0_r[EPT], pk_r[EPT], rk_r[EPT];
        int s0a[EPT], s1a[EPT];
        float dwa[EPT], gea_a[EPT];
        bool anyv = base_off < tn;
        if (base_off + EPT <= tn) {
            // vector loads (tileLo 16-aligned, base_off multiple of 8)
            const int4* p0 = (const int4*)(ei0 + tileLo + base_off);
            const int4* p1 = (const int4*)(ei1 + tileLo + base_off);
            const float4* pd = (const float4*)(dw + tileLo + base_off);
            const float4* pg = (const float4*)(gea + tileLo + base_off);
            int4 a0 = p0[0], a1 = p0[1];
            int4 b0 = p1[0], b1 = p1[1];
            float4 d0 = pd[0], d1 = pd[1];
            float4 g0 = pg[0], g1 = pg[1];
            s0a[0]=a0.x; s0a[1]=a0.y; s0a[2]=a0.z; s0a[3]=a0.w;
            s0a[4]=a1.x; s0a[5]=a1.y; s0a[6]=a1.z; s0a[7]=a1.w;
            s1a[0]=b0.x; s1a[1]=b0.y; s1a[2]=b0.z; s1a[3]=b0.w;
            s1a[4]=b1.x; s1a[5]=b1.y; s1a[6]=b1.z; s1a[7]=b1.w;
            dwa[0]=d0.x; dwa[1]=d0.y; dwa[2]=d0.z; dwa[3]=d0.w;
            dwa[4]=d1.x; dwa[5]=d1.y; dwa[6]=d1.z; dwa[7]=d1.w;
            gea_a[0]=g0.x; gea_a[1]=g0.y; gea_a[2]=g0.z; gea_a[3]=g0.w;
            gea_a[4]=g1.x; gea_a[5]=g1.y; gea_a[6]=g1.z; gea_a[7]=g1.w;
#pragma unroll
            for (int j = 0; j < EPT; ++j) k_r[j] = 0u;   // mark all valid below
#pragma unroll
            for (int j = 0; j < EPT; ++j) {
                unsigned k = (unsigned)s0a[j] >> S_LOG;
                unsigned s0l = (unsigned)(s0a[j] & (SBUCKET - 1));
                k_r[j] = k;
                w0_r[j] = (unsigned)s1a[j] | (s0l << 17);
                float sig = 1.0f / (1.0f + __expf(-dwa[j]));
                pk_r[j] = (bf16hi(__float_as_uint(sqrtf(sig))) << 16) |
                          bf16hi(__float_as_uint(gea_a[j]));
            }
#pragma unroll
            for (int j = 0; j < EPT; ++j)
                rk_r[j] = atomicAdd(&h[k_r[j]], 1u);
        } else {
#pragma unroll
            for (int j = 0; j < EPT; ++j) {
                int off = base_off + j;
                k_r[j] = 0xFFFFFFFFu;
                if (off < tn) {
                    int i = tileLo + off;
                    int s0v = ei0[i];
                    int s1v = ei1[i];
                    unsigned k = (unsigned)s0v >> S_LOG;
                    unsigned s0l = (unsigned)(s0v & (SBUCKET - 1));
                    k_r[j] = k;
                    w0_r[j] = (unsigned)s1v | (s0l << 17);
                    float sig = 1.0f / (1.0f + __expf(-dw[i]));
                    pk_r[j] = (bf16hi(__float_as_uint(sqrtf(sig))) << 16) |
                              bf16hi(__float_as_uint(gea[i]));
                }
            }
#pragma unroll
            for (int j = 0; j < EPT; ++j)
                if (k_r[j] != 0xFFFFFFFFu) rk_r[j] = atomicAdd(&h[k_r[j]], 1u);
        }
        bool fullv = base_off + EPT <= tn;
        __syncthreads();

        // exclusive scan of h[256] via wave shuffles
        unsigned hv = h[tid];
        unsigned v = hv;
        unsigned lane = tid & 63;
        unsigned wv = tid >> 6;
#pragma unroll
        for (int off = 1; off < 64; off <<= 1) {
            unsigned t = __shfl_up(v, off, 64);
            if (lane >= off) v += t;
        }
        if (lane == 63) wsum[wv] = v;
        __syncthreads();
        unsigned addv = 0;
#pragma unroll
        for (unsigned w = 0; w < 4; ++w)
            if (w < wv) addv += wsum[w];
        tstart[tid] = v + addv - hv;
        __syncthreads();

        if (fullv) {
#pragma unroll
            for (int j = 0; j < EPT; ++j) {
                unsigned slot = tstart[k_r[j]] + rk_r[j];
                srec[slot] = make_uint2(w0_r[j], pk_r[j]);
                skey[slot] = (unsigned char)k_r[j];
            }
        } else if (anyv) {
#pragma unroll
            for (int j = 0; j < EPT; ++j)
                if (k_r[j] != 0xFFFFFFFFu) {
                    unsigned slot = tstart[k_r[j]] + rk_r[j];
                    srec[slot] = make_uint2(w0_r[j], pk_r[j]);
                    skey[slot] = (unsigned char)k_r[j];
                }
        }
        __syncthreads();

        for (int i = tid; i < tn; i += 256) {
            uint2 u = srec[i];
            unsigned k = skey[i];
            unsigned pos = cursor[k] + ((unsigned)i - tstart[k]);
            w0coef[pos] = u;
        }
        __syncthreads();
        cursor[tid] += h[tid];
        __syncthreads();
    }
}

// accum (owner-computes): one block per bucket, 512 threads, 1 node/thread.
// Per chunk (<=SCAP records): load the chunk ONCE into registers (rec[RPT],
// static indices), count s0l via LDS atomics, 8-wave scan, scatter from
// registers into node-sorted LDS — no second global read of w0coef (R9).
// Then each thread walks its node's contiguous run accumulating in fp32
// registers. Writes final out = 1 - acc/deg^2 directly.
__global__ __launch_bounds__(512)
void accum_kernel(const uint2* __restrict__ w0coef, const unsigned* __restrict__ bb,
                  const uint4* __restrict__ yT,
                  float* __restrict__ out, int N) {
    __shared__ uint2 srt[SCAP];              // 120 KB sorted records
    __shared__ unsigned bcnt[SBUCKET];       // 2 KB per-node count (chunk)
    __shared__ unsigned bcur[SBUCKET];       // 2 KB scatter cursors
    __shared__ unsigned wsums[8];
    int k = blockIdx.x, tid = threadIdx.x;
    int n0 = k << S_LOG;
    unsigned lane = tid & 63;
    unsigned wvi = tid >> 6;

    unsigned lo = bb[k], hi = bb[k + 1];

    // my node's y0, unpacked once
    uint4 y0r = yT[n0 + tid];
    float y0f[8];
    {
        unsigned yw[4] = {y0r.x, y0r.y, y0r.z, y0r.w};
#pragma unroll
        for (int p = 0; p < 4; ++p) {
            y0f[2 * p]     = __uint_as_float(yw[p] << 16);
            y0f[2 * p + 1] = __uint_as_float(yw[p] & 0xFFFF0000u);
        }
    }
    float acc[8] = {0.f, 0.f, 0.f, 0.f, 0.f, 0.f, 0.f, 0.f};
    float dega = 0.f;

    for (unsigned cbase = lo; cbase < hi; cbase += SCAP) {
        unsigned cn = min((unsigned)SCAP, hi - cbase);
        bcnt[tid] = 0u;
        __syncthreads();
        // single coalesced global read of the chunk into registers
        uint2 rec[RPT];
#pragma unroll
        for (int j = 0; j < RPT; ++j) {
            unsigned o = (unsigned)tid + (unsigned)j * 512u;
            rec[j] = (o < cn) ? w0coef[cbase + o] : make_uint2(0u, 0u);
        }
        // pass1: count s0l from registers (cheap uint LDS atomics)
#pragma unroll
        for (int j = 0; j < RPT; ++j) {
            unsigned o = (unsigned)tid + (unsigned)j * 512u;
            if (o < cn) atomicAdd(&bcnt[rec[j].x >> 17], 1u);
        }
        __syncthreads();
        // exclusive scan of bcnt[512] across 8 waves
        unsigned myc = bcnt[tid];
        unsigned v = myc;
#pragma unroll
        for (int off = 1; off < 64; off <<= 1) {
            unsigned t = __shfl_up(v, off, 64);
            if (lane >= off) v += t;
        }
        if (lane == 63) wsums[wvi] = v;
        __syncthreads();
        unsigned add = 0;
#pragma unroll
        for (unsigned w = 0; w < 8; ++w)
            if (w < wvi) add += wsums[w];
        unsigned myoff = v + add - myc;
        bcur[tid] = myoff;
        __syncthreads();
        // pass2: scatter from registers into srt sorted by node
#pragma unroll
        for (int j = 0; j < RPT; ++j) {
            unsigned o = (unsigned)tid + (unsigned)j * 512u;
            if (o < cn) {
                unsigned slot = atomicAdd(&bcur[rec[j].x >> 17], 1u);
                srt[slot] = rec[j];
            }
        }
        __syncthreads();
        // owner phase: walk my run with a 2-deep prefetch pipeline
        unsigned s = myoff, e = myoff + myc;
        uint2 r0 = make_uint2(0u, 0u), r1 = make_uint2(0u, 0u);
        uint4 g0 = make_uint4(0u, 0u, 0u, 0u), g1 = g0;
        if (s < e)     { r0 = srt[s];     g0 = yT[r0.x & 0x1FFFFu]; }
        if (s + 1 < e) { r1 = srt[s + 1]; g1 = yT[r1.x & 0x1FFFFu]; }
        for (unsigned i = s; i < e; ++i) {
            uint2 rc = r0; uint4 gc = g0;
            r0 = r1; g0 = g1;
            if (i + 2 < e) { r1 = srt[i + 2]; g1 = yT[r1.x & 0x1FFFFu]; }
            float cf = __uint_as_float(rc.y & 0xFFFF0000u);
            float ge = __uint_as_float(rc.y << 16);
            unsigned gw[4] = {gc.x, gc.y, gc.z, gc.w};
#pragma unroll
            for (int p = 0; p < 4; ++p) {
                float ga = __uint_as_float(gw[p] << 16);
                float gb = __uint_as_float(gw[p] & 0xFFFF0000u);
                acc[2 * p]     += cf * fmaxf(y0f[2 * p]     - ga, 0.0f);
                acc[2 * p + 1] += cf * fmaxf(y0f[2 * p + 1] - gb, 0.0f);
            }
            dega += ge;
        }
        __syncthreads();   // all owners done before LDS reuse next chunk
    }

    // final write: out[b*N + n] = 1 - acc[b]/deg^2 (coalesced per batch)
    int n = n0 + tid;
    if (n < N) {
        float invd = (dega != 0.0f) ? 1.0f / (dega * dega) : 0.0f;
#pragma unroll
        for (int b = 0; b < BATCH; ++b)
            out[(size_t)b * N + n] = 1.0f - acc[b] * invd;
    }
}

// ---------------- fallback (R1 path) ----------------

__global__ void fill_one_kernel(float* __restrict__ out, int n) {
    int i = blockIdx.x * blockDim.x + threadIdx.x;
    if (i < n) out[i] = 1.0f;
}

__global__ void zero_kernel(float* __restrict__ p, int n) {
    int i = blockIdx.x * blockDim.x + threadIdx.x;
    if (i < n) p[i] = 0.0f;
}

__global__ void deg_kernel(const float* __restrict__ gea,
                           const int* __restrict__ ei0,
                           float* __restrict__ deg, int E) {
    int e = blockIdx.x * blockDim.x + threadIdx.x;
    if (e < E) atomicAdd(&deg[ei0[e]], gea[e]);
}

__global__ void edge_kernel(const float* __restrict__ y,
                            const float* __restrict__ dw,
                            const int* __restrict__ ei0,
                            const int* __restrict__ ei1,
                            const float* __restrict__ deg,
                            float* __restrict__ out,
                            int E, int N) {
    int e = blockIdx.x * blockDim.x + threadIdx.x;
    if (e >= E) return;
    int s0 = ei0[e];
    int s1 = ei1[e];
    float d = deg[s0];
    float inv = 1.0f / (d * d);
    float sig = 1.0f / (1.0f + __expf(-dw[e]));
    float coef = sqrtf(sig) * inv;
#pragma unroll
    for (int b = 0; b < BATCH; ++b) {
        float y0 = y[(size_t)b * N + s0];
        float y1 = y[(size_t)b * N + s1];
        float gm = coef * fmaxf(y0 - y1, 0.0f);
        if (gm != 0.0f) atomicAdd(&out[(size_t)b * N + s0], -gm);
    }
}

// ---------------- launch ----------------

extern "C" void kernel_launch(void* const* d_in, const int* in_sizes, int n_in,
                              void* d_out, int out_size, void* d_ws, size_t ws_size,
                              hipStream_t stream) {
    const float* y   = (const float*)d_in[0];   // [B,N]
    const float* gea = (const float*)d_in[2];   // [E]
    const float* dw  = (const float*)d_in[3];   // [E]
    const int*   ei  = (const int*)d_in[4];     // [2,E]

    const int E = in_sizes[2];
    const int N = in_sizes[0] / BATCH;
    const int* ei0 = ei;
    const int* ei1 = ei + E;

    const int K = (N + SBUCKET - 1) >> S_LOG;
    const int Npad = K << S_LOG;

    size_t o_yT     = 0;
    size_t o_rcf    = o_yT     + alignup((size_t)Npad * 16);
    size_t o_counts = o_rcf    + alignup((size_t)E * 8);
    size_t o_base   = o_counts + alignup((size_t)KC * CB * 4);
    size_t o_tot    = o_base   + alignup((size_t)KC * CB * 4);
    size_t o_bb     = o_tot    + alignup((size_t)KC * 4);
    size_t need     = o_bb     + alignup((size_t)(KC + 1) * 4);

    if (K <= KC && N <= 131071 && ws_size >= need) {
        char* w = (char*)d_ws;
        uint4*    yT     = (uint4*)(w + o_yT);
        uint2*    w0coef = (uint2*)(w + o_rcf);
        unsigned* counts = (unsigned*)(w + o_counts);
        unsigned* base   = (unsigned*)(w + o_base);
        unsigned* tot    = (unsigned*)(w + o_tot);
        unsigned* bb     = (unsigned*)(w + o_bb);

        int tb = (Npad + 255) / 256;
        count_transpose_kernel<<<CB + tb, 256, 0, stream>>>(ei0, counts, y, yT,
                                                            E, N, Npad);
        scanB1_kernel<<<K, 256, 0, stream>>>(counts, base, tot);
        scanC_kernel<<<1, KC, 0, stream>>>(tot, bb, E, K);
        scatter_kernel<<<CB, 256, 0, stream>>>(ei0, ei1, dw, gea, base, bb,
                                               w0coef, E);
        accum_kernel<<<K, 512, 0, stream>>>(w0coef, bb, yT, (float*)d_out, N);
    } else {
        float* deg = (float*)d_ws;
        zero_kernel<<<(N + 255) / 256, 256, 0, stream>>>(deg, N);
        fill_one_kernel<<<(out_size + 255) / 256, 256, 0, stream>>>((float*)d_out, out_size);
        deg_kernel<<<(E + 255) / 256, 256, 0, stream>>>(gea, ei0, deg, E);
        edge_kernel<<<(E + 255) / 256, 256, 0, stream>>>(y, dw, ei0, ei1, deg,
                                                         (float*)d_out, E, N);
    }
}